// Round 8
// baseline (757.544 us; speedup 1.0000x reference)
//
#include <hip/hip_runtime.h>
#include <hip/hip_bf16.h>
#include <cmath>

typedef __attribute__((ext_vector_type(8))) short s8v;   // 8 bf16 (4 VGPR) MFMA operand / 16B chunk
typedef __attribute__((ext_vector_type(4))) float f4v;   // MFMA accumulator

__device__ __forceinline__ f4v mf(s8v a, s8v b, f4v c) {
    return __builtin_amdgcn_mfma_f32_16x16x32_bf16(a, b, c, 0, 0, 0);
}

// RNE float -> bf16 bits (finite inputs only)
__device__ __forceinline__ short bf16_of(float f) {
    unsigned u = __builtin_bit_cast(unsigned, f);
    unsigned r = (u + 0x7FFFu + ((u >> 16) & 1u)) >> 16;
    return (short)r;
}
__device__ __forceinline__ float f_of_bf16(short h) {
    return __builtin_bit_cast(float, ((unsigned)(unsigned short)h) << 16);
}
__device__ __forceinline__ void split2(float v, short& h, short& l) {
    short hh = bf16_of(v);
    h = hh;
    l = bf16_of(v - f_of_bf16(hh));
}

// ---------------------------------------------------------------------------
// Prep 1: z (zr|zi fp32 [4096][1024] each) -> Zhi/Zlo bf16 [4096][2048]
// ---------------------------------------------------------------------------
__global__ __launch_bounds__(256) void prep_z(
    const float* __restrict__ zr, const float* __restrict__ zi,
    short* __restrict__ Zhi, short* __restrict__ Zlo)
{
    int idx = blockIdx.x * 256 + threadIdx.x;        // 0 .. 4096*512-1
    int m = idx >> 9, kq = idx & 511;                // kq = float4 index in 2048-col row
    const float* src = (kq < 256) ? (zr + (size_t)m * 1024 + kq * 4)
                                  : (zi + (size_t)m * 1024 + (kq - 256) * 4);
    float4 v = *reinterpret_cast<const float4*>(src);
    ushort4 hi, lo;
    short h, l;
    split2(v.x, h, l); hi.x = h; lo.x = l;
    split2(v.y, h, l); hi.y = h; lo.y = l;
    split2(v.z, h, l); hi.z = h; lo.z = l;
    split2(v.w, h, l); hi.w = h; lo.w = l;
    *reinterpret_cast<ushort4*>(&Zhi[(size_t)m * 2048 + kq * 4]) = hi;
    *reinterpret_cast<ushort4*>(&Zlo[(size_t)m * 2048 + kq * 4]) = lo;
}

// ---------------------------------------------------------------------------
// Prep 2: q/k/v weights -> packed B [6144][2048] hi/lo bf16 (signs baked).
// ---------------------------------------------------------------------------
__global__ __launch_bounds__(256) void prep_wqkv(
    const float* __restrict__ qwr, const float* __restrict__ qwi,
    const float* __restrict__ kwr, const float* __restrict__ kwi,
    const float* __restrict__ vwr, const float* __restrict__ vwi,
    short* __restrict__ Bqh, short* __restrict__ Bql)
{
    int idx = blockIdx.x * 256 + threadIdx.x;        // 0 .. 6144*512-1
    int n = idx >> 9, kq = idx & 511;
    int k = kq * 4;
    int t = n >> 11, cpart = (n >> 10) & 1, o = n & 1023;
    const float* Wr = (t == 0) ? qwr : (t == 1) ? kwr : vwr;
    const float* Wi = (t == 0) ? qwi : (t == 1) ? kwi : vwi;
    const float* W;
    float sgn;
    int kk;
    if (k < 1024) { W = cpart ? Wi : Wr; sgn = 1.f; kk = k; }
    else          { W = cpart ? Wr : Wi; sgn = cpart ? 1.f : -1.f; kk = k - 1024; }
    float4 v = *reinterpret_cast<const float4*>(W + (size_t)o * 1024 + kk);
    ushort4 hi, lo;
    short h, l;
    split2(sgn * v.x, h, l); hi.x = h; lo.x = l;
    split2(sgn * v.y, h, l); hi.y = h; lo.y = l;
    split2(sgn * v.z, h, l); hi.z = h; lo.z = l;
    split2(sgn * v.w, h, l); hi.w = h; lo.w = l;
    *reinterpret_cast<ushort4*>(&Bqh[(size_t)n * 2048 + k]) = hi;
    *reinterpret_cast<ushort4*>(&Bql[(size_t)n * 2048 + k]) = lo;
}

// ---------------------------------------------------------------------------
// Prep 3: o weights -> packed Bo [2048][2048] bf16 (hi only, signs baked)
// ---------------------------------------------------------------------------
__global__ __launch_bounds__(256) void prep_wo(
    const float* __restrict__ owr, const float* __restrict__ owi,
    short* __restrict__ Boh)
{
    int idx = blockIdx.x * 256 + threadIdx.x;        // 0 .. 2048*512-1
    int n = idx >> 9, kq = idx & 511;
    int k = kq * 4;
    int part = n >> 10, o = n & 1023;
    const float* W;
    float sgn;
    int kk;
    if (k < 1024) { W = part ? owi : owr; sgn = 1.f; kk = k; }
    else          { W = part ? owr : owi; sgn = part ? 1.f : -1.f; kk = k - 1024; }
    float4 v = *reinterpret_cast<const float4*>(W + (size_t)o * 1024 + kk);
    ushort4 hi;
    hi.x = (unsigned short)bf16_of(sgn * v.x);
    hi.y = (unsigned short)bf16_of(sgn * v.y);
    hi.z = (unsigned short)bf16_of(sgn * v.z);
    hi.w = (unsigned short)bf16_of(sgn * v.w);
    *reinterpret_cast<ushort4*>(&Boh[(size_t)n * 2048 + k]) = hi;
}

// ---------------------------------------------------------------------------
// GEMM-Q: [4096 x 2048] x [2048 x 2048] (Q cols only), 3-pass bf16 split.
// ---------------------------------------------------------------------------
__global__ __launch_bounds__(256) void gemm_q(
    const short* __restrict__ Zhi, const short* __restrict__ Zlo,
    const short* __restrict__ Bqh, const short* __restrict__ Bql,
    short* __restrict__ QKhi, short* __restrict__ QKlo)
{
    __shared__ __align__(16) short Ah[128][40], Al[128][40], Bh[128][40], Bl[128][40];
    const int tid = threadIdx.x;
    const int lane = tid & 63, wid = tid >> 6;
    const int c = lane & 15, g = lane >> 4;
    const int wr = wid >> 1, wc = wid & 1;
    const int nt = blockIdx.x, mt = blockIdx.y;
    const int m0 = mt * 128, n0 = nt * 128;

    const f4v zero4 = {0.f, 0.f, 0.f, 0.f};
    f4v acc[4][4];
#pragma unroll
    for (int mi = 0; mi < 4; ++mi)
#pragma unroll
        for (int ni = 0; ni < 4; ++ni) acc[mi][ni] = zero4;

    const int r2 = tid >> 2;            // 0..63
    const int koff = (tid & 3) * 8;     // 0,8,16,24

    for (int kt = 0; kt < 64; ++kt) {
        const int k0 = kt * 32;
        __syncthreads();
#pragma unroll
        for (int half = 0; half < 2; ++half) {
            int row = half * 64 + r2;
            size_t ga = (size_t)(m0 + row) * 2048 + k0 + koff;
            size_t gb = (size_t)(n0 + row) * 2048 + k0 + koff;
            *reinterpret_cast<s8v*>(&Ah[row][koff]) = *reinterpret_cast<const s8v*>(&Zhi[ga]);
            *reinterpret_cast<s8v*>(&Al[row][koff]) = *reinterpret_cast<const s8v*>(&Zlo[ga]);
            *reinterpret_cast<s8v*>(&Bh[row][koff]) = *reinterpret_cast<const s8v*>(&Bqh[gb]);
            *reinterpret_cast<s8v*>(&Bl[row][koff]) = *reinterpret_cast<const s8v*>(&Bql[gb]);
        }
        __syncthreads();

        s8v ah[4], alo[4], bh[4], blo[4];
#pragma unroll
        for (int i = 0; i < 4; ++i) {
            ah[i]  = *reinterpret_cast<const s8v*>(&Ah[wr * 64 + i * 16 + c][8 * g]);
            alo[i] = *reinterpret_cast<const s8v*>(&Al[wr * 64 + i * 16 + c][8 * g]);
            bh[i]  = *reinterpret_cast<const s8v*>(&Bh[wc * 64 + i * 16 + c][8 * g]);
            blo[i] = *reinterpret_cast<const s8v*>(&Bl[wc * 64 + i * 16 + c][8 * g]);
        }
        __builtin_amdgcn_s_setprio(1);
#pragma unroll
        for (int mi = 0; mi < 4; ++mi)
#pragma unroll
            for (int ni = 0; ni < 4; ++ni) {
                acc[mi][ni] = mf(ah[mi], bh[ni], acc[mi][ni]);
                acc[mi][ni] = mf(ah[mi], blo[ni], acc[mi][ni]);
                acc[mi][ni] = mf(alo[mi], bh[ni], acc[mi][ni]);
            }
        __builtin_amdgcn_s_setprio(0);
    }

    // epilogue: cols all < 2048 -> Q hi + lo
#pragma unroll
    for (int mi = 0; mi < 4; ++mi) {
#pragma unroll
        for (int ni = 0; ni < 4; ++ni) {
            int col = n0 + wc * 64 + ni * 16 + c;
            int rbase = m0 + wr * 64 + mi * 16 + 4 * g;
#pragma unroll
            for (int j = 0; j < 4; ++j) {
                short h, l;
                split2(acc[mi][ni][j], h, l);
                QKhi[(size_t)(rbase + j) * 4096 + col] = h;
                QKlo[(size_t)(rbase + j) * 2048 + col] = l;
            }
        }
    }
}

// ---------------------------------------------------------------------------
// GEMM-KV: [4096 x 2048] x [2048 x 4096] (K,V cols), single bf16 pass.
// ---------------------------------------------------------------------------
__global__ __launch_bounds__(256) void gemm_kv(
    const short* __restrict__ Zhi,
    const short* __restrict__ Bqh,
    short* __restrict__ QKhi,
    short* __restrict__ Vtr, short* __restrict__ Vti)
{
    __shared__ __align__(16) short Ah[128][40], Bh[128][40];
    const int tid = threadIdx.x;
    const int lane = tid & 63, wid = tid >> 6;
    const int c = lane & 15, g = lane >> 4;
    const int wr = wid >> 1, wc = wid & 1;
    const int nt = blockIdx.x, mt = blockIdx.y;
    const int m0 = mt * 128, n0 = 2048 + nt * 128;

    const f4v zero4 = {0.f, 0.f, 0.f, 0.f};
    f4v acc[4][4];
#pragma unroll
    for (int mi = 0; mi < 4; ++mi)
#pragma unroll
        for (int ni = 0; ni < 4; ++ni) acc[mi][ni] = zero4;

    const int r2 = tid >> 2;            // 0..63
    const int koff = (tid & 3) * 8;     // 0,8,16,24

    for (int kt = 0; kt < 64; ++kt) {
        const int k0 = kt * 32;
        __syncthreads();
#pragma unroll
        for (int half = 0; half < 2; ++half) {
            int row = half * 64 + r2;
            size_t ga = (size_t)(m0 + row) * 2048 + k0 + koff;
            size_t gb = (size_t)(n0 + row) * 2048 + k0 + koff;
            *reinterpret_cast<s8v*>(&Ah[row][koff]) = *reinterpret_cast<const s8v*>(&Zhi[ga]);
            *reinterpret_cast<s8v*>(&Bh[row][koff]) = *reinterpret_cast<const s8v*>(&Bqh[gb]);
        }
        __syncthreads();

        s8v ah[4], bh[4];
#pragma unroll
        for (int i = 0; i < 4; ++i) {
            ah[i] = *reinterpret_cast<const s8v*>(&Ah[wr * 64 + i * 16 + c][8 * g]);
            bh[i] = *reinterpret_cast<const s8v*>(&Bh[wc * 64 + i * 16 + c][8 * g]);
        }
        __builtin_amdgcn_s_setprio(1);
#pragma unroll
        for (int mi = 0; mi < 4; ++mi)
#pragma unroll
            for (int ni = 0; ni < 4; ++ni)
                acc[mi][ni] = mf(ah[mi], bh[ni], acc[mi][ni]);
        __builtin_amdgcn_s_setprio(0);
    }

    // epilogue: K cols -> QKhi; V cols -> V^T
#pragma unroll
    for (int mi = 0; mi < 4; ++mi) {
#pragma unroll
        for (int ni = 0; ni < 4; ++ni) {
            int col = n0 + wc * 64 + ni * 16 + c;
            int rbase = m0 + wr * 64 + mi * 16 + 4 * g;
            if (col < 4096) {
#pragma unroll
                for (int j = 0; j < 4; ++j)
                    QKhi[(size_t)(rbase + j) * 4096 + col] = bf16_of(acc[mi][ni][j]);
            } else {
                int cc = col - 4096;
                int part = cc >> 10, o = cc & 1023;
                int hh = o >> 6, d = o & 63;
                int bb = rbase >> 11, s = rbase & 2047;
                short* vt = part ? Vti : Vtr;
                ushort4 pk;
                pk.x = (unsigned short)bf16_of(acc[mi][ni][0]);
                pk.y = (unsigned short)bf16_of(acc[mi][ni][1]);
                pk.z = (unsigned short)bf16_of(acc[mi][ni][2]);
                pk.w = (unsigned short)bf16_of(acc[mi][ni][3]);
                *reinterpret_cast<ushort4*>(&vt[((size_t)(bb * 16 + hh) * 64 + d) * 2048 + s]) = pk;
            }
        }
    }
}

// ---------------------------------------------------------------------------
// Fused flash attention, barrier-free: K and V both read directly from
// global (L2-resident per XCD via swizzle) into registers; no LDS staging,
// no __syncthreads, no split-K. Swapped QK^T (mfma(K,Q)): lane's 16 scores
// all on query row q=c -> packed cvt_pk P-writes, scalar row-sum. Flattened
// softmax (scores in [0,44.2] -> no max subtraction). p_lds per-wave,
// padded rows (68 shorts) to reduce bank aliasing.
// ---------------------------------------------------------------------------
__global__ __launch_bounds__(256, 4) void attn_fused(
    const short* __restrict__ QKhi, const short* __restrict__ QKlo,
    const short* __restrict__ Vtr, const short* __restrict__ Vti,
    short* __restrict__ aout)
{
    __shared__ __align__(16) short p_lds[4][16][68];   // 8.5 KB, per-wave tiles
    const int tid = threadIdx.x, lane = tid & 63, wid = tid >> 6;
    const int c = lane & 15, g = lane >> 4;

    // XCD swizzle: all 32 q-tiles of one (b,h) on one XCD.
    const int L = blockIdx.x;                    // 0..1023
    const int idx = L >> 3;                      // 0..127
    const int p = (L & 7) + ((idx >> 5) << 3);   // (b,h) pair 0..31
    const int qt = idx & 31;
    const int h = p & 15, b = p >> 4;

    const int q0 = qt * 64 + wid * 16;
    const int mq = b * 2048 + q0 + c;

    s8v qrh[2], qrl[2], qih[2], qil[2], nqrh[2], nqrl[2];
#pragma unroll
    for (int ks = 0; ks < 2; ++ks) {
        int colr = h * 64 + ks * 32 + 8 * g;
        qrh[ks] = *reinterpret_cast<const s8v*>(&QKhi[(size_t)mq * 4096 + colr]);
        qrl[ks] = *reinterpret_cast<const s8v*>(&QKlo[(size_t)mq * 2048 + colr]);
        qih[ks] = *reinterpret_cast<const s8v*>(&QKhi[(size_t)mq * 4096 + 1024 + colr]);
        qil[ks] = *reinterpret_cast<const s8v*>(&QKlo[(size_t)mq * 2048 + 1024 + colr]);
        nqrh[ks] = qrh[ks] ^ (short)0x8000;
        nqrl[ks] = qrl[ks] ^ (short)0x8000;
    }

    const f4v zero4 = {0.f, 0.f, 0.f, 0.f};
    f4v aor[4], aoi[4];
#pragma unroll
    for (int dt = 0; dt < 4; ++dt) { aor[dt] = zero4; aoi[dt] = zero4; }
    float lrun = 0.f;        // all of this lane's scores belong to q = q0 + c

    // exp(s*0.125) == exp2(s*0.125*log2e)
    const float ESC = 0.125f * 1.44269504f;

    // K row base (col part fixed): row stride 4096 shorts
    const short* Kbase = QKhi + (size_t)(b * 2048) * 4096 + 2048 + h * 64;
    const size_t vb0 = (size_t)((b * 16 + h) * 64) * 2048;

    for (int kt = 0; kt < 32; ++kt) {
        const int ktb = kt * 64;
#pragma unroll
        for (int kn = 0; kn < 4; ++kn) {
            f4v sr = zero4, si = zero4;
            const short* krow = Kbase + (size_t)(ktb + kn * 16 + c) * 4096;
#pragma unroll
            for (int ks = 0; ks < 2; ++ks) {
                s8v krh = *reinterpret_cast<const s8v*>(krow + ks * 32 + 8 * g);
                s8v kih = *reinterpret_cast<const s8v*>(krow + 1024 + ks * 32 + 8 * g);
                // swapped operands: lane(c,g) reg j = S[q=c][k=kn*16+4g+j]
                sr = mf(krh, qrh[ks], sr); sr = mf(krh, qrl[ks], sr);
                sr = mf(kih, qih[ks], sr); sr = mf(kih, qil[ks], sr);
                si = mf(krh, qih[ks], si); si = mf(krh, qil[ks], si);
                si = mf(kih, nqrh[ks], si); si = mf(kih, nqrl[ks], si);
            }
            float pv0, pv1, pv2, pv3;
            {
                float a, e;
                a = sr[0]; e = si[0]; pv0 = exp2f(sqrtf(__builtin_fmaf(e, e, a * a)) * ESC);
                a = sr[1]; e = si[1]; pv1 = exp2f(sqrtf(__builtin_fmaf(e, e, a * a)) * ESC);
                a = sr[2]; e = si[2]; pv2 = exp2f(sqrtf(__builtin_fmaf(e, e, a * a)) * ESC);
                a = sr[3]; e = si[3]; pv3 = exp2f(sqrtf(__builtin_fmaf(e, e, a * a)) * ESC);
            }
            lrun += (pv0 + pv1) + (pv2 + pv3);
            unsigned lo32, hi32;
            asm("v_cvt_pk_bf16_f32 %0, %1, %2" : "=v"(lo32) : "v"(pv0), "v"(pv1));
            asm("v_cvt_pk_bf16_f32 %0, %1, %2" : "=v"(hi32) : "v"(pv2), "v"(pv3));
            const int widx = (kn * 16 + 4 * g) ^ ((c & 7) << 3);
            uint2 pk2; pk2.x = lo32; pk2.y = hi32;
            *reinterpret_cast<uint2*>(&p_lds[wid][c][widx]) = pk2;
        }

        const size_t vbase = vb0 + ktb;
#pragma unroll
        for (int ks = 0; ks < 2; ++ks) {
            s8v pa = *reinterpret_cast<const s8v*>(
                &p_lds[wid][c][(ks * 32 + 8 * g) ^ ((c & 7) << 3)]);
#pragma unroll
            for (int dt = 0; dt < 4; ++dt) {
                size_t va = vbase + (size_t)(dt * 16 + c) * 2048 + ks * 32 + 8 * g;
                s8v vr = *reinterpret_cast<const s8v*>(&Vtr[va]);
                s8v vi = *reinterpret_cast<const s8v*>(&Vti[va]);
                aor[dt] = mf(pa, vr, aor[dt]);
                aoi[dt] = mf(pa, vi, aoi[dt]);
            }
        }
    }

    // row-sum over the 4 g-groups (lanes c, c+16, c+32, c+48 share q=q0+c)
    float rt = lrun;
    rt += __shfl_xor(rt, 16);
    rt += __shfl_xor(rt, 32);
    // O rows are q = q0 + 4g + j -> fetch l for those rows
    f4v ilv;
#pragma unroll
    for (int j = 0; j < 4; ++j) ilv[j] = 1.f / __shfl(rt, 4 * g + j);

#pragma unroll
    for (int dt = 0; dt < 4; ++dt) {
        f4v orv = aor[dt] * ilv, oiv = aoi[dt] * ilv;
#pragma unroll
        for (int j = 0; j < 4; ++j) {
            int row = b * 2048 + q0 + 4 * g + j;
            aout[(size_t)row * 2048 + h * 64 + dt * 16 + c] = bf16_of(orv[j]);
            aout[(size_t)row * 2048 + 1024 + h * 64 + dt * 16 + c] = bf16_of(oiv[j]);
        }
    }
}

// ---------------------------------------------------------------------------
// GEMM2: attn_out [4096 x 2048] x packed o_w bf16 [2048 x 2048] -> yr|yi fp32
// ---------------------------------------------------------------------------
__global__ __launch_bounds__(256) void gemm_out(
    const short* __restrict__ A,
    const short* __restrict__ Boh,
    float* __restrict__ out)
{
    __shared__ __align__(16) short Ah[128][40], Bh[128][40];
    const int tid = threadIdx.x;
    const int lane = tid & 63, wid = tid >> 6;
    const int c = lane & 15, g = lane >> 4;
    const int wr = wid >> 1, wc = wid & 1;
    const int nt = blockIdx.x, mt = blockIdx.y;
    const int m0 = mt * 128, n0 = nt * 128;

    const f4v zero4 = {0.f, 0.f, 0.f, 0.f};
    f4v acc[4][4];
#pragma unroll
    for (int mi = 0; mi < 4; ++mi)
#pragma unroll
        for (int ni = 0; ni < 4; ++ni) acc[mi][ni] = zero4;

    const int r2 = tid >> 2;
    const int koff = (tid & 3) * 8;

    for (int kt = 0; kt < 64; ++kt) {
        const int k0 = kt * 32;
        __syncthreads();
#pragma unroll
        for (int half = 0; half < 2; ++half) {
            int row = half * 64 + r2;
            *reinterpret_cast<s8v*>(&Ah[row][koff]) =
                *reinterpret_cast<const s8v*>(&A[(size_t)(m0 + row) * 2048 + k0 + koff]);
            *reinterpret_cast<s8v*>(&Bh[row][koff]) =
                *reinterpret_cast<const s8v*>(&Boh[(size_t)(n0 + row) * 2048 + k0 + koff]);
        }
        __syncthreads();

        s8v af[4], bfr[4];
#pragma unroll
        for (int i = 0; i < 4; ++i) {
            af[i]  = *reinterpret_cast<const s8v*>(&Ah[wr * 64 + i * 16 + c][8 * g]);
            bfr[i] = *reinterpret_cast<const s8v*>(&Bh[wc * 64 + i * 16 + c][8 * g]);
        }
        __builtin_amdgcn_s_setprio(1);
#pragma unroll
        for (int mi = 0; mi < 4; ++mi)
#pragma unroll
            for (int ni = 0; ni < 4; ++ni)
                acc[mi][ni] = mf(af[mi], bfr[ni], acc[mi][ni]);
        __builtin_amdgcn_s_setprio(0);
    }

#pragma unroll
    for (int mi = 0; mi < 4; ++mi)
#pragma unroll
        for (int ni = 0; ni < 4; ++ni) {
            int col = n0 + wc * 64 + ni * 16 + c;
#pragma unroll
            for (int j = 0; j < 4; ++j) {
                int row = m0 + wr * 64 + mi * 16 + 4 * g + j;
                float v = acc[mi][ni][j];
                if (col < 1024) out[(size_t)row * 1024 + col] = v;
                else out[4194304 + (size_t)row * 1024 + (col - 1024)] = v;
            }
        }
}

extern "C" void kernel_launch(void* const* d_in, const int* in_sizes, int n_in,
                              void* d_out, int out_size, void* d_ws, size_t ws_size,
                              hipStream_t stream) {
    const float* zr  = (const float*)d_in[0];
    const float* zi  = (const float*)d_in[1];
    const float* qwr = (const float*)d_in[2];
    const float* qwi = (const float*)d_in[3];
    const float* kwr = (const float*)d_in[4];
    const float* kwi = (const float*)d_in[5];
    const float* vwr = (const float*)d_in[6];
    const float* vwi = (const float*)d_in[7];
    const float* owr = (const float*)d_in[8];
    const float* owi = (const float*)d_in[9];

    char* ws = (char*)d_ws;
    short* QKhi = (short*)(ws);                      // 33554432 B
    short* QKlo = (short*)(ws + 33554432);           // 16777216 B (Q cols only)
    short* Vtr  = (short*)(ws + 50331648);           //  8388608 B
    short* Vti  = (short*)(ws + 58720256);           //  8388608 B
    short* aout = (short*)(ws + 67108864);           // 16777216 B
    short* Zhi  = (short*)(ws + 83886080);           // 16777216 B
    short* Zlo  = (short*)(ws + 100663296);          // 16777216 B
    short* Bqh  = (short*)(ws + 117440512);          // 25165824 B
    short* Bql  = (short*)(ws + 142606336);          // 25165824 B
    short* Boh  = (short*)(ws + 167772160);          //  8388608 B  (total 176160768)

    prep_z<<<dim3(8192), 256, 0, stream>>>(zr, zi, Zhi, Zlo);
    prep_wqkv<<<dim3(12288), 256, 0, stream>>>(qwr, qwi, kwr, kwi, vwr, vwi, Bqh, Bql);
    prep_wo<<<dim3(4096), 256, 0, stream>>>(owr, owi, Boh);
    gemm_q<<<dim3(16, 32, 1), 256, 0, stream>>>(Zhi, Zlo, Bqh, Bql, QKhi, QKlo);
    gemm_kv<<<dim3(32, 32, 1), 256, 0, stream>>>(Zhi, Bqh, QKhi, Vtr, Vti);
    attn_fused<<<dim3(1024), 256, 0, stream>>>(QKhi, QKlo, Vtr, Vti, aout);
    gemm_out<<<dim3(16, 32, 1), 256, 0, stream>>>(aout, Boh, (float*)d_out);
}

// Round 9
// 753.959 us; speedup vs baseline: 1.0048x; 1.0048x over previous
//
#include <hip/hip_runtime.h>
#include <hip/hip_bf16.h>
#include <cmath>

typedef __attribute__((ext_vector_type(8))) short s8v;   // 8 bf16 (4 VGPR) MFMA operand / 16B chunk
typedef __attribute__((ext_vector_type(4))) float f4v;   // MFMA accumulator

__device__ __forceinline__ f4v mf(s8v a, s8v b, f4v c) {
    return __builtin_amdgcn_mfma_f32_16x16x32_bf16(a, b, c, 0, 0, 0);
}

// RNE float -> bf16 bits (finite inputs only)
__device__ __forceinline__ short bf16_of(float f) {
    unsigned u = __builtin_bit_cast(unsigned, f);
    unsigned r = (u + 0x7FFFu + ((u >> 16) & 1u)) >> 16;
    return (short)r;
}
__device__ __forceinline__ float f_of_bf16(short h) {
    return __builtin_bit_cast(float, ((unsigned)(unsigned short)h) << 16);
}
__device__ __forceinline__ void split2(float v, short& h, short& l) {
    short hh = bf16_of(v);
    h = hh;
    l = bf16_of(v - f_of_bf16(hh));
}

// ---------------------------------------------------------------------------
// Prep 1: z (zr|zi fp32 [4096][1024] each) -> Zhi/Zlo bf16 [4096][2048]
// ---------------------------------------------------------------------------
__global__ __launch_bounds__(256) void prep_z(
    const float* __restrict__ zr, const float* __restrict__ zi,
    short* __restrict__ Zhi, short* __restrict__ Zlo)
{
    int idx = blockIdx.x * 256 + threadIdx.x;        // 0 .. 4096*512-1
    int m = idx >> 9, kq = idx & 511;                // kq = float4 index in 2048-col row
    const float* src = (kq < 256) ? (zr + (size_t)m * 1024 + kq * 4)
                                  : (zi + (size_t)m * 1024 + (kq - 256) * 4);
    float4 v = *reinterpret_cast<const float4*>(src);
    ushort4 hi, lo;
    short h, l;
    split2(v.x, h, l); hi.x = h; lo.x = l;
    split2(v.y, h, l); hi.y = h; lo.y = l;
    split2(v.z, h, l); hi.z = h; lo.z = l;
    split2(v.w, h, l); hi.w = h; lo.w = l;
    *reinterpret_cast<ushort4*>(&Zhi[(size_t)m * 2048 + kq * 4]) = hi;
    *reinterpret_cast<ushort4*>(&Zlo[(size_t)m * 2048 + kq * 4]) = lo;
}

// ---------------------------------------------------------------------------
// Prep 2: q/k/v weights -> packed B [6144][2048] hi/lo bf16 (signs baked).
// ---------------------------------------------------------------------------
__global__ __launch_bounds__(256) void prep_wqkv(
    const float* __restrict__ qwr, const float* __restrict__ qwi,
    const float* __restrict__ kwr, const float* __restrict__ kwi,
    const float* __restrict__ vwr, const float* __restrict__ vwi,
    short* __restrict__ Bqh, short* __restrict__ Bql)
{
    int idx = blockIdx.x * 256 + threadIdx.x;        // 0 .. 6144*512-1
    int n = idx >> 9, kq = idx & 511;
    int k = kq * 4;
    int t = n >> 11, cpart = (n >> 10) & 1, o = n & 1023;
    const float* Wr = (t == 0) ? qwr : (t == 1) ? kwr : vwr;
    const float* Wi = (t == 0) ? qwi : (t == 1) ? kwi : vwi;
    const float* W;
    float sgn;
    int kk;
    if (k < 1024) { W = cpart ? Wi : Wr; sgn = 1.f; kk = k; }
    else          { W = cpart ? Wr : Wi; sgn = cpart ? 1.f : -1.f; kk = k - 1024; }
    float4 v = *reinterpret_cast<const float4*>(W + (size_t)o * 1024 + kk);
    ushort4 hi, lo;
    short h, l;
    split2(sgn * v.x, h, l); hi.x = h; lo.x = l;
    split2(sgn * v.y, h, l); hi.y = h; lo.y = l;
    split2(sgn * v.z, h, l); hi.z = h; lo.z = l;
    split2(sgn * v.w, h, l); hi.w = h; lo.w = l;
    *reinterpret_cast<ushort4*>(&Bqh[(size_t)n * 2048 + k]) = hi;
    *reinterpret_cast<ushort4*>(&Bql[(size_t)n * 2048 + k]) = lo;
}

// ---------------------------------------------------------------------------
// Prep 3: o weights -> packed Bo [2048][2048] bf16 (hi only, signs baked)
// ---------------------------------------------------------------------------
__global__ __launch_bounds__(256) void prep_wo(
    const float* __restrict__ owr, const float* __restrict__ owi,
    short* __restrict__ Boh)
{
    int idx = blockIdx.x * 256 + threadIdx.x;        // 0 .. 2048*512-1
    int n = idx >> 9, kq = idx & 511;
    int k = kq * 4;
    int part = n >> 10, o = n & 1023;
    const float* W;
    float sgn;
    int kk;
    if (k < 1024) { W = part ? owi : owr; sgn = 1.f; kk = k; }
    else          { W = part ? owr : owi; sgn = part ? 1.f : -1.f; kk = k - 1024; }
    float4 v = *reinterpret_cast<const float4*>(W + (size_t)o * 1024 + kk);
    ushort4 hi;
    hi.x = (unsigned short)bf16_of(sgn * v.x);
    hi.y = (unsigned short)bf16_of(sgn * v.y);
    hi.z = (unsigned short)bf16_of(sgn * v.z);
    hi.w = (unsigned short)bf16_of(sgn * v.w);
    *reinterpret_cast<ushort4*>(&Boh[(size_t)n * 2048 + k]) = hi;
}

// ---------------------------------------------------------------------------
// GEMM-Q: [4096 x 2048] x [2048 x 2048] (Q cols only), 3-pass bf16 split.
// ---------------------------------------------------------------------------
__global__ __launch_bounds__(256) void gemm_q(
    const short* __restrict__ Zhi, const short* __restrict__ Zlo,
    const short* __restrict__ Bqh, const short* __restrict__ Bql,
    short* __restrict__ QKhi, short* __restrict__ QKlo)
{
    __shared__ __align__(16) short Ah[128][40], Al[128][40], Bh[128][40], Bl[128][40];
    const int tid = threadIdx.x;
    const int lane = tid & 63, wid = tid >> 6;
    const int c = lane & 15, g = lane >> 4;
    const int wr = wid >> 1, wc = wid & 1;
    const int nt = blockIdx.x, mt = blockIdx.y;
    const int m0 = mt * 128, n0 = nt * 128;

    const f4v zero4 = {0.f, 0.f, 0.f, 0.f};
    f4v acc[4][4];
#pragma unroll
    for (int mi = 0; mi < 4; ++mi)
#pragma unroll
        for (int ni = 0; ni < 4; ++ni) acc[mi][ni] = zero4;

    const int r2 = tid >> 2;            // 0..63
    const int koff = (tid & 3) * 8;     // 0,8,16,24

    for (int kt = 0; kt < 64; ++kt) {
        const int k0 = kt * 32;
        __syncthreads();
#pragma unroll
        for (int half = 0; half < 2; ++half) {
            int row = half * 64 + r2;
            size_t ga = (size_t)(m0 + row) * 2048 + k0 + koff;
            size_t gb = (size_t)(n0 + row) * 2048 + k0 + koff;
            *reinterpret_cast<s8v*>(&Ah[row][koff]) = *reinterpret_cast<const s8v*>(&Zhi[ga]);
            *reinterpret_cast<s8v*>(&Al[row][koff]) = *reinterpret_cast<const s8v*>(&Zlo[ga]);
            *reinterpret_cast<s8v*>(&Bh[row][koff]) = *reinterpret_cast<const s8v*>(&Bqh[gb]);
            *reinterpret_cast<s8v*>(&Bl[row][koff]) = *reinterpret_cast<const s8v*>(&Bql[gb]);
        }
        __syncthreads();

        s8v ah[4], alo[4], bh[4], blo[4];
#pragma unroll
        for (int i = 0; i < 4; ++i) {
            ah[i]  = *reinterpret_cast<const s8v*>(&Ah[wr * 64 + i * 16 + c][8 * g]);
            alo[i] = *reinterpret_cast<const s8v*>(&Al[wr * 64 + i * 16 + c][8 * g]);
            bh[i]  = *reinterpret_cast<const s8v*>(&Bh[wc * 64 + i * 16 + c][8 * g]);
            blo[i] = *reinterpret_cast<const s8v*>(&Bl[wc * 64 + i * 16 + c][8 * g]);
        }
        __builtin_amdgcn_s_setprio(1);
#pragma unroll
        for (int mi = 0; mi < 4; ++mi)
#pragma unroll
            for (int ni = 0; ni < 4; ++ni) {
                acc[mi][ni] = mf(ah[mi], bh[ni], acc[mi][ni]);
                acc[mi][ni] = mf(ah[mi], blo[ni], acc[mi][ni]);
                acc[mi][ni] = mf(alo[mi], bh[ni], acc[mi][ni]);
            }
        __builtin_amdgcn_s_setprio(0);
    }

    // epilogue: cols all < 2048 -> Q hi + lo
#pragma unroll
    for (int mi = 0; mi < 4; ++mi) {
#pragma unroll
        for (int ni = 0; ni < 4; ++ni) {
            int col = n0 + wc * 64 + ni * 16 + c;
            int rbase = m0 + wr * 64 + mi * 16 + 4 * g;
#pragma unroll
            for (int j = 0; j < 4; ++j) {
                short h, l;
                split2(acc[mi][ni][j], h, l);
                QKhi[(size_t)(rbase + j) * 4096 + col] = h;
                QKlo[(size_t)(rbase + j) * 2048 + col] = l;
            }
        }
    }
}

// ---------------------------------------------------------------------------
// GEMM-KV: [4096 x 2048] x [2048 x 4096] (K,V cols), single bf16 pass.
// ---------------------------------------------------------------------------
__global__ __launch_bounds__(256) void gemm_kv(
    const short* __restrict__ Zhi,
    const short* __restrict__ Bqh,
    short* __restrict__ QKhi,
    short* __restrict__ Vtr, short* __restrict__ Vti)
{
    __shared__ __align__(16) short Ah[128][40], Bh[128][40];
    const int tid = threadIdx.x;
    const int lane = tid & 63, wid = tid >> 6;
    const int c = lane & 15, g = lane >> 4;
    const int wr = wid >> 1, wc = wid & 1;
    const int nt = blockIdx.x, mt = blockIdx.y;
    const int m0 = mt * 128, n0 = 2048 + nt * 128;

    const f4v zero4 = {0.f, 0.f, 0.f, 0.f};
    f4v acc[4][4];
#pragma unroll
    for (int mi = 0; mi < 4; ++mi)
#pragma unroll
        for (int ni = 0; ni < 4; ++ni) acc[mi][ni] = zero4;

    const int r2 = tid >> 2;            // 0..63
    const int koff = (tid & 3) * 8;     // 0,8,16,24

    for (int kt = 0; kt < 64; ++kt) {
        const int k0 = kt * 32;
        __syncthreads();
#pragma unroll
        for (int half = 0; half < 2; ++half) {
            int row = half * 64 + r2;
            size_t ga = (size_t)(m0 + row) * 2048 + k0 + koff;
            size_t gb = (size_t)(n0 + row) * 2048 + k0 + koff;
            *reinterpret_cast<s8v*>(&Ah[row][koff]) = *reinterpret_cast<const s8v*>(&Zhi[ga]);
            *reinterpret_cast<s8v*>(&Bh[row][koff]) = *reinterpret_cast<const s8v*>(&Bqh[gb]);
        }
        __syncthreads();

        s8v ah[4], bh[4];
#pragma unroll
        for (int i = 0; i < 4; ++i) {
            ah[i] = *reinterpret_cast<const s8v*>(&Ah[wr * 64 + i * 16 + c][8 * g]);
            bh[i] = *reinterpret_cast<const s8v*>(&Bh[wc * 64 + i * 16 + c][8 * g]);
        }
        __builtin_amdgcn_s_setprio(1);
#pragma unroll
        for (int mi = 0; mi < 4; ++mi)
#pragma unroll
            for (int ni = 0; ni < 4; ++ni)
                acc[mi][ni] = mf(ah[mi], bh[ni], acc[mi][ni]);
        __builtin_amdgcn_s_setprio(0);
    }

    // epilogue: K cols -> QKhi; V cols -> V^T
#pragma unroll
    for (int mi = 0; mi < 4; ++mi) {
#pragma unroll
        for (int ni = 0; ni < 4; ++ni) {
            int col = n0 + wc * 64 + ni * 16 + c;
            int rbase = m0 + wr * 64 + mi * 16 + 4 * g;
            if (col < 4096) {
#pragma unroll
                for (int j = 0; j < 4; ++j)
                    QKhi[(size_t)(rbase + j) * 4096 + col] = bf16_of(acc[mi][ni][j]);
            } else {
                int cc = col - 4096;
                int part = cc >> 10, o = cc & 1023;
                int hh = o >> 6, d = o & 63;
                int bb = rbase >> 11, s = rbase & 2047;
                short* vt = part ? Vti : Vtr;
                ushort4 pk;
                pk.x = (unsigned short)bf16_of(acc[mi][ni][0]);
                pk.y = (unsigned short)bf16_of(acc[mi][ni][1]);
                pk.z = (unsigned short)bf16_of(acc[mi][ni][2]);
                pk.w = (unsigned short)bf16_of(acc[mi][ni][3]);
                *reinterpret_cast<ushort4*>(&vt[((size_t)(bb * 16 + hh) * 64 + d) * 2048 + s]) = pk;
            }
        }
    }
}

// ---------------------------------------------------------------------------
// Fused flash attention, barrier-free with explicit software pipelining:
// - V tile for kt held in registers (16 s8v), reloaded for kt+1 right after
//   PV consumes it -> latency hides under next kt's QK phase.
// - K double-buffered at kn granularity: issue kn+1 loads before computing kn.
// - launch_bounds(256,2): VGPR budget ~200 so all prefetches stay in flight
//   (round-8 lesson: VGPR=64 serializes every load at L2 latency).
// Swapped QK^T (mfma(K,Q)), flattened softmax, per-wave padded p_lds.
// ---------------------------------------------------------------------------
__global__ __launch_bounds__(256, 2) void attn_fused(
    const short* __restrict__ QKhi, const short* __restrict__ QKlo,
    const short* __restrict__ Vtr, const short* __restrict__ Vti,
    short* __restrict__ aout)
{
    __shared__ __align__(16) short p_lds[4][16][68];   // 8.5 KB, per-wave tiles
    const int tid = threadIdx.x, lane = tid & 63, wid = tid >> 6;
    const int c = lane & 15, g = lane >> 4;

    // XCD swizzle: all 32 q-tiles of one (b,h) on one XCD.
    const int L = blockIdx.x;                    // 0..1023
    const int idx = L >> 3;                      // 0..127
    const int p = (L & 7) + ((idx >> 5) << 3);   // (b,h) pair 0..31
    const int qt = idx & 31;
    const int h = p & 15, b = p >> 4;

    const int q0 = qt * 64 + wid * 16;
    const int mq = b * 2048 + q0 + c;

    s8v qrh[2], qrl[2], qih[2], qil[2], nqrh[2], nqrl[2];
#pragma unroll
    for (int ks = 0; ks < 2; ++ks) {
        int colr = h * 64 + ks * 32 + 8 * g;
        qrh[ks] = *reinterpret_cast<const s8v*>(&QKhi[(size_t)mq * 4096 + colr]);
        qrl[ks] = *reinterpret_cast<const s8v*>(&QKlo[(size_t)mq * 2048 + colr]);
        qih[ks] = *reinterpret_cast<const s8v*>(&QKhi[(size_t)mq * 4096 + 1024 + colr]);
        qil[ks] = *reinterpret_cast<const s8v*>(&QKlo[(size_t)mq * 2048 + 1024 + colr]);
        nqrh[ks] = qrh[ks] ^ (short)0x8000;
        nqrl[ks] = qrl[ks] ^ (short)0x8000;
    }

    const f4v zero4 = {0.f, 0.f, 0.f, 0.f};
    f4v aor[4], aoi[4];
#pragma unroll
    for (int dt = 0; dt < 4; ++dt) { aor[dt] = zero4; aoi[dt] = zero4; }
    float lrun = 0.f;        // all of this lane's scores belong to q = q0 + c

    // exp(s*0.125) == exp2(s*0.125*log2e)
    const float ESC = 0.125f * 1.44269504f;

    const short* Kbase = QKhi + (size_t)(b * 2048) * 4096 + 2048 + h * 64;
    const size_t vb0 = (size_t)((b * 16 + h) * 64) * 2048;

    // --- prime V regs (whole kt=0 tile, 16 s8v) ---
    s8v vrr[2][4], vri[2][4];
#pragma unroll
    for (int ks = 0; ks < 2; ++ks)
#pragma unroll
        for (int dt = 0; dt < 4; ++dt) {
            size_t va = vb0 + (size_t)(dt * 16 + c) * 2048 + ks * 32 + 8 * g;
            vrr[ks][dt] = *reinterpret_cast<const s8v*>(&Vtr[va]);
            vri[ks][dt] = *reinterpret_cast<const s8v*>(&Vti[va]);
        }

    // --- prime K regs (kt=0, kn=0) ---
    s8v kch[2], kci[2];
    {
        const short* krow = Kbase + (size_t)c * 4096;
#pragma unroll
        for (int ks = 0; ks < 2; ++ks) {
            kch[ks] = *reinterpret_cast<const s8v*>(krow + ks * 32 + 8 * g);
            kci[ks] = *reinterpret_cast<const s8v*>(krow + 1024 + ks * 32 + 8 * g);
        }
    }

    for (int kt = 0; kt < 32; ++kt) {
        const int ktb = kt * 64;
        const int ktn = (kt + 1) & 31;           // wrap: last prefetch harmless
#pragma unroll
        for (int kn = 0; kn < 4; ++kn) {
            // issue next K loads (kn+1 of this kt, or kn=0 of kt+1)
            s8v knh[2], kni[2];
            {
                const int nktb = (kn == 3) ? ktn * 64 : ktb;
                const int nkn = (kn + 1) & 3;
                const short* krow = Kbase + (size_t)(nktb + nkn * 16 + c) * 4096;
#pragma unroll
                for (int ks = 0; ks < 2; ++ks) {
                    knh[ks] = *reinterpret_cast<const s8v*>(krow + ks * 32 + 8 * g);
                    kni[ks] = *reinterpret_cast<const s8v*>(krow + 1024 + ks * 32 + 8 * g);
                }
            }
            // QK^T with current K (swapped operands: lane(c,g) reg j = S[q=c][k=kn*16+4g+j])
            f4v sr = zero4, si = zero4;
#pragma unroll
            for (int ks = 0; ks < 2; ++ks) {
                sr = mf(kch[ks], qrh[ks], sr); sr = mf(kch[ks], qrl[ks], sr);
                sr = mf(kci[ks], qih[ks], sr); sr = mf(kci[ks], qil[ks], sr);
                si = mf(kch[ks], qih[ks], si); si = mf(kch[ks], qil[ks], si);
                si = mf(kci[ks], nqrh[ks], si); si = mf(kci[ks], nqrl[ks], si);
            }
            float pv0, pv1, pv2, pv3;
            {
                float a, e;
                a = sr[0]; e = si[0]; pv0 = exp2f(sqrtf(__builtin_fmaf(e, e, a * a)) * ESC);
                a = sr[1]; e = si[1]; pv1 = exp2f(sqrtf(__builtin_fmaf(e, e, a * a)) * ESC);
                a = sr[2]; e = si[2]; pv2 = exp2f(sqrtf(__builtin_fmaf(e, e, a * a)) * ESC);
                a = sr[3]; e = si[3]; pv3 = exp2f(sqrtf(__builtin_fmaf(e, e, a * a)) * ESC);
            }
            lrun += (pv0 + pv1) + (pv2 + pv3);
            unsigned lo32, hi32;
            asm("v_cvt_pk_bf16_f32 %0, %1, %2" : "=v"(lo32) : "v"(pv0), "v"(pv1));
            asm("v_cvt_pk_bf16_f32 %0, %1, %2" : "=v"(hi32) : "v"(pv2), "v"(pv3));
            const int widx = (kn * 16 + 4 * g) ^ ((c & 7) << 3);
            uint2 pk2; pk2.x = lo32; pk2.y = hi32;
            *reinterpret_cast<uint2*>(&p_lds[wid][c][widx]) = pk2;
            // rotate K buffer
#pragma unroll
            for (int ks = 0; ks < 2; ++ks) { kch[ks] = knh[ks]; kci[ks] = kni[ks]; }
        }

        // PV with register-held V tile
#pragma unroll
        for (int ks = 0; ks < 2; ++ks) {
            s8v pa = *reinterpret_cast<const s8v*>(
                &p_lds[wid][c][(ks * 32 + 8 * g) ^ ((c & 7) << 3)]);
#pragma unroll
            for (int dt = 0; dt < 4; ++dt) {
                aor[dt] = mf(pa, vrr[ks][dt], aor[dt]);
                aoi[dt] = mf(pa, vri[ks][dt], aoi[dt]);
            }
        }

        // reload V regs for kt+1 (latency hides under next kt's QK phase)
#pragma unroll
        for (int ks = 0; ks < 2; ++ks)
#pragma unroll
            for (int dt = 0; dt < 4; ++dt) {
                size_t va = vb0 + ktn * 64 + (size_t)(dt * 16 + c) * 2048 + ks * 32 + 8 * g;
                vrr[ks][dt] = *reinterpret_cast<const s8v*>(&Vtr[va]);
                vri[ks][dt] = *reinterpret_cast<const s8v*>(&Vti[va]);
            }
    }

    // row-sum over the 4 g-groups (lanes c, c+16, c+32, c+48 share q=q0+c)
    float rt = lrun;
    rt += __shfl_xor(rt, 16);
    rt += __shfl_xor(rt, 32);
    // O rows are q = q0 + 4g + j -> fetch l for those rows
    f4v ilv;
#pragma unroll
    for (int j = 0; j < 4; ++j) ilv[j] = 1.f / __shfl(rt, 4 * g + j);

#pragma unroll
    for (int dt = 0; dt < 4; ++dt) {
        f4v orv = aor[dt] * ilv, oiv = aoi[dt] * ilv;
#pragma unroll
        for (int j = 0; j < 4; ++j) {
            int row = b * 2048 + q0 + 4 * g + j;
            aout[(size_t)row * 2048 + h * 64 + dt * 16 + c] = bf16_of(orv[j]);
            aout[(size_t)row * 2048 + 1024 + h * 64 + dt * 16 + c] = bf16_of(oiv[j]);
        }
    }
}

// ---------------------------------------------------------------------------
// GEMM2: attn_out [4096 x 2048] x packed o_w bf16 [2048 x 2048] -> yr|yi fp32
// ---------------------------------------------------------------------------
__global__ __launch_bounds__(256) void gemm_out(
    const short* __restrict__ A,
    const short* __restrict__ Boh,
    float* __restrict__ out)
{
    __shared__ __align__(16) short Ah[128][40], Bh[128][40];
    const int tid = threadIdx.x;
    const int lane = tid & 63, wid = tid >> 6;
    const int c = lane & 15, g = lane >> 4;
    const int wr = wid >> 1, wc = wid & 1;
    const int nt = blockIdx.x, mt = blockIdx.y;
    const int m0 = mt * 128, n0 = nt * 128;

    const f4v zero4 = {0.f, 0.f, 0.f, 0.f};
    f4v acc[4][4];
#pragma unroll
    for (int mi = 0; mi < 4; ++mi)
#pragma unroll
        for (int ni = 0; ni < 4; ++ni) acc[mi][ni] = zero4;

    const int r2 = tid >> 2;
    const int koff = (tid & 3) * 8;

    for (int kt = 0; kt < 64; ++kt) {
        const int k0 = kt * 32;
        __syncthreads();
#pragma unroll
        for (int half = 0; half < 2; ++half) {
            int row = half * 64 + r2;
            *reinterpret_cast<s8v*>(&Ah[row][koff]) =
                *reinterpret_cast<const s8v*>(&A[(size_t)(m0 + row) * 2048 + k0 + koff]);
            *reinterpret_cast<s8v*>(&Bh[row][koff]) =
                *reinterpret_cast<const s8v*>(&Boh[(size_t)(n0 + row) * 2048 + k0 + koff]);
        }
        __syncthreads();

        s8v af[4], bfr[4];
#pragma unroll
        for (int i = 0; i < 4; ++i) {
            af[i]  = *reinterpret_cast<const s8v*>(&Ah[wr * 64 + i * 16 + c][8 * g]);
            bfr[i] = *reinterpret_cast<const s8v*>(&Bh[wc * 64 + i * 16 + c][8 * g]);
        }
        __builtin_amdgcn_s_setprio(1);
#pragma unroll
        for (int mi = 0; mi < 4; ++mi)
#pragma unroll
            for (int ni = 0; ni < 4; ++ni)
                acc[mi][ni] = mf(af[mi], bfr[ni], acc[mi][ni]);
        __builtin_amdgcn_s_setprio(0);
    }

#pragma unroll
    for (int mi = 0; mi < 4; ++mi)
#pragma unroll
        for (int ni = 0; ni < 4; ++ni) {
            int col = n0 + wc * 64 + ni * 16 + c;
#pragma unroll
            for (int j = 0; j < 4; ++j) {
                int row = m0 + wr * 64 + mi * 16 + 4 * g + j;
                float v = acc[mi][ni][j];
                if (col < 1024) out[(size_t)row * 1024 + col] = v;
                else out[4194304 + (size_t)row * 1024 + (col - 1024)] = v;
            }
        }
}

extern "C" void kernel_launch(void* const* d_in, const int* in_sizes, int n_in,
                              void* d_out, int out_size, void* d_ws, size_t ws_size,
                              hipStream_t stream) {
    const float* zr  = (const float*)d_in[0];
    const float* zi  = (const float*)d_in[1];
    const float* qwr = (const float*)d_in[2];
    const float* qwi = (const float*)d_in[3];
    const float* kwr = (const float*)d_in[4];
    const float* kwi = (const float*)d_in[5];
    const float* vwr = (const float*)d_in[6];
    const float* vwi = (const float*)d_in[7];
    const float* owr = (const float*)d_in[8];
    const float* owi = (const float*)d_in[9];

    char* ws = (char*)d_ws;
    short* QKhi = (short*)(ws);                      // 33554432 B
    short* QKlo = (short*)(ws + 33554432);           // 16777216 B (Q cols only)
    short* Vtr  = (short*)(ws + 50331648);           //  8388608 B
    short* Vti  = (short*)(ws + 58720256);           //  8388608 B
    short* aout = (short*)(ws + 67108864);           // 16777216 B
    short* Zhi  = (short*)(ws + 83886080);           // 16777216 B
    short* Zlo  = (short*)(ws + 100663296);          // 16777216 B
    short* Bqh  = (short*)(ws + 117440512);          // 25165824 B
    short* Bql  = (short*)(ws + 142606336);          // 25165824 B
    short* Boh  = (short*)(ws + 167772160);          //  8388608 B  (total 176160768)

    prep_z<<<dim3(8192), 256, 0, stream>>>(zr, zi, Zhi, Zlo);
    prep_wqkv<<<dim3(12288), 256, 0, stream>>>(qwr, qwi, kwr, kwi, vwr, vwi, Bqh, Bql);
    prep_wo<<<dim3(4096), 256, 0, stream>>>(owr, owi, Boh);
    gemm_q<<<dim3(16, 32, 1), 256, 0, stream>>>(Zhi, Zlo, Bqh, Bql, QKhi, QKlo);
    gemm_kv<<<dim3(32, 32, 1), 256, 0, stream>>>(Zhi, Bqh, QKhi, Vtr, Vti);
    attn_fused<<<dim3(1024), 256, 0, stream>>>(QKhi, QKlo, Vtr, Vti, aout);
    gemm_out<<<dim3(16, 32, 1), 256, 0, stream>>>(aout, Boh, (float*)d_out);
}

// Round 10
// 610.316 us; speedup vs baseline: 1.2412x; 1.2354x over previous
//
#include <hip/hip_runtime.h>
#include <hip/hip_bf16.h>
#include <cmath>

typedef __attribute__((ext_vector_type(8))) short s8v;   // 8 bf16 (4 VGPR) MFMA operand / 16B chunk
typedef __attribute__((ext_vector_type(4))) float f4v;   // MFMA accumulator

__device__ __forceinline__ f4v mf(s8v a, s8v b, f4v c) {
    return __builtin_amdgcn_mfma_f32_16x16x32_bf16(a, b, c, 0, 0, 0);
}

// RNE float -> bf16 bits (finite inputs only)
__device__ __forceinline__ short bf16_of(float f) {
    unsigned u = __builtin_bit_cast(unsigned, f);
    unsigned r = (u + 0x7FFFu + ((u >> 16) & 1u)) >> 16;
    return (short)r;
}
__device__ __forceinline__ float f_of_bf16(short h) {
    return __builtin_bit_cast(float, ((unsigned)(unsigned short)h) << 16);
}
__device__ __forceinline__ void split2(float v, short& h, short& l) {
    short hh = bf16_of(v);
    h = hh;
    l = bf16_of(v - f_of_bf16(hh));
}

// ---------------------------------------------------------------------------
// Prep 1: z (zr|zi fp32 [4096][1024] each) -> Zhi/Zlo bf16 [4096][2048]
// ---------------------------------------------------------------------------
__global__ __launch_bounds__(256) void prep_z(
    const float* __restrict__ zr, const float* __restrict__ zi,
    short* __restrict__ Zhi, short* __restrict__ Zlo)
{
    int idx = blockIdx.x * 256 + threadIdx.x;        // 0 .. 4096*512-1
    int m = idx >> 9, kq = idx & 511;                // kq = float4 index in 2048-col row
    const float* src = (kq < 256) ? (zr + (size_t)m * 1024 + kq * 4)
                                  : (zi + (size_t)m * 1024 + (kq - 256) * 4);
    float4 v = *reinterpret_cast<const float4*>(src);
    ushort4 hi, lo;
    short h, l;
    split2(v.x, h, l); hi.x = h; lo.x = l;
    split2(v.y, h, l); hi.y = h; lo.y = l;
    split2(v.z, h, l); hi.z = h; lo.z = l;
    split2(v.w, h, l); hi.w = h; lo.w = l;
    *reinterpret_cast<ushort4*>(&Zhi[(size_t)m * 2048 + kq * 4]) = hi;
    *reinterpret_cast<ushort4*>(&Zlo[(size_t)m * 2048 + kq * 4]) = lo;
}

// ---------------------------------------------------------------------------
// Prep 2: q/k/v weights -> packed B [6144][2048] hi/lo bf16 (signs baked).
// ---------------------------------------------------------------------------
__global__ __launch_bounds__(256) void prep_wqkv(
    const float* __restrict__ qwr, const float* __restrict__ qwi,
    const float* __restrict__ kwr, const float* __restrict__ kwi,
    const float* __restrict__ vwr, const float* __restrict__ vwi,
    short* __restrict__ Bqh, short* __restrict__ Bql)
{
    int idx = blockIdx.x * 256 + threadIdx.x;        // 0 .. 6144*512-1
    int n = idx >> 9, kq = idx & 511;
    int k = kq * 4;
    int t = n >> 11, cpart = (n >> 10) & 1, o = n & 1023;
    const float* Wr = (t == 0) ? qwr : (t == 1) ? kwr : vwr;
    const float* Wi = (t == 0) ? qwi : (t == 1) ? kwi : vwi;
    const float* W;
    float sgn;
    int kk;
    if (k < 1024) { W = cpart ? Wi : Wr; sgn = 1.f; kk = k; }
    else          { W = cpart ? Wr : Wi; sgn = cpart ? 1.f : -1.f; kk = k - 1024; }
    float4 v = *reinterpret_cast<const float4*>(W + (size_t)o * 1024 + kk);
    ushort4 hi, lo;
    short h, l;
    split2(sgn * v.x, h, l); hi.x = h; lo.x = l;
    split2(sgn * v.y, h, l); hi.y = h; lo.y = l;
    split2(sgn * v.z, h, l); hi.z = h; lo.z = l;
    split2(sgn * v.w, h, l); hi.w = h; lo.w = l;
    *reinterpret_cast<ushort4*>(&Bqh[(size_t)n * 2048 + k]) = hi;
    *reinterpret_cast<ushort4*>(&Bql[(size_t)n * 2048 + k]) = lo;
}

// ---------------------------------------------------------------------------
// Prep 3: o weights -> packed Bo [2048][2048] bf16 (hi only, signs baked)
// ---------------------------------------------------------------------------
__global__ __launch_bounds__(256) void prep_wo(
    const float* __restrict__ owr, const float* __restrict__ owi,
    short* __restrict__ Boh)
{
    int idx = blockIdx.x * 256 + threadIdx.x;        // 0 .. 2048*512-1
    int n = idx >> 9, kq = idx & 511;
    int k = kq * 4;
    int part = n >> 10, o = n & 1023;
    const float* W;
    float sgn;
    int kk;
    if (k < 1024) { W = part ? owi : owr; sgn = 1.f; kk = k; }
    else          { W = part ? owr : owi; sgn = part ? 1.f : -1.f; kk = k - 1024; }
    float4 v = *reinterpret_cast<const float4*>(W + (size_t)o * 1024 + kk);
    ushort4 hi;
    hi.x = (unsigned short)bf16_of(sgn * v.x);
    hi.y = (unsigned short)bf16_of(sgn * v.y);
    hi.z = (unsigned short)bf16_of(sgn * v.z);
    hi.w = (unsigned short)bf16_of(sgn * v.w);
    *reinterpret_cast<ushort4*>(&Boh[(size_t)n * 2048 + k]) = hi;
}

// ---------------------------------------------------------------------------
// GEMM-Q: [4096 x 2048] x [2048 x 2048] (Q cols only), 3-pass bf16 split.
// ---------------------------------------------------------------------------
__global__ __launch_bounds__(256) void gemm_q(
    const short* __restrict__ Zhi, const short* __restrict__ Zlo,
    const short* __restrict__ Bqh, const short* __restrict__ Bql,
    short* __restrict__ QKhi, short* __restrict__ QKlo)
{
    __shared__ __align__(16) short Ah[128][40], Al[128][40], Bh[128][40], Bl[128][40];
    const int tid = threadIdx.x;
    const int lane = tid & 63, wid = tid >> 6;
    const int c = lane & 15, g = lane >> 4;
    const int wr = wid >> 1, wc = wid & 1;
    const int nt = blockIdx.x, mt = blockIdx.y;
    const int m0 = mt * 128, n0 = nt * 128;

    const f4v zero4 = {0.f, 0.f, 0.f, 0.f};
    f4v acc[4][4];
#pragma unroll
    for (int mi = 0; mi < 4; ++mi)
#pragma unroll
        for (int ni = 0; ni < 4; ++ni) acc[mi][ni] = zero4;

    const int r2 = tid >> 2;            // 0..63
    const int koff = (tid & 3) * 8;     // 0,8,16,24

    for (int kt = 0; kt < 64; ++kt) {
        const int k0 = kt * 32;
        __syncthreads();
#pragma unroll
        for (int half = 0; half < 2; ++half) {
            int row = half * 64 + r2;
            size_t ga = (size_t)(m0 + row) * 2048 + k0 + koff;
            size_t gb = (size_t)(n0 + row) * 2048 + k0 + koff;
            *reinterpret_cast<s8v*>(&Ah[row][koff]) = *reinterpret_cast<const s8v*>(&Zhi[ga]);
            *reinterpret_cast<s8v*>(&Al[row][koff]) = *reinterpret_cast<const s8v*>(&Zlo[ga]);
            *reinterpret_cast<s8v*>(&Bh[row][koff]) = *reinterpret_cast<const s8v*>(&Bqh[gb]);
            *reinterpret_cast<s8v*>(&Bl[row][koff]) = *reinterpret_cast<const s8v*>(&Bql[gb]);
        }
        __syncthreads();

        s8v ah[4], alo[4], bh[4], blo[4];
#pragma unroll
        for (int i = 0; i < 4; ++i) {
            ah[i]  = *reinterpret_cast<const s8v*>(&Ah[wr * 64 + i * 16 + c][8 * g]);
            alo[i] = *reinterpret_cast<const s8v*>(&Al[wr * 64 + i * 16 + c][8 * g]);
            bh[i]  = *reinterpret_cast<const s8v*>(&Bh[wc * 64 + i * 16 + c][8 * g]);
            blo[i] = *reinterpret_cast<const s8v*>(&Bl[wc * 64 + i * 16 + c][8 * g]);
        }
        __builtin_amdgcn_s_setprio(1);
#pragma unroll
        for (int mi = 0; mi < 4; ++mi)
#pragma unroll
            for (int ni = 0; ni < 4; ++ni) {
                acc[mi][ni] = mf(ah[mi], bh[ni], acc[mi][ni]);
                acc[mi][ni] = mf(ah[mi], blo[ni], acc[mi][ni]);
                acc[mi][ni] = mf(alo[mi], bh[ni], acc[mi][ni]);
            }
        __builtin_amdgcn_s_setprio(0);
    }

    // epilogue: cols all < 2048 -> Q hi + lo
#pragma unroll
    for (int mi = 0; mi < 4; ++mi) {
#pragma unroll
        for (int ni = 0; ni < 4; ++ni) {
            int col = n0 + wc * 64 + ni * 16 + c;
            int rbase = m0 + wr * 64 + mi * 16 + 4 * g;
#pragma unroll
            for (int j = 0; j < 4; ++j) {
                short h, l;
                split2(acc[mi][ni][j], h, l);
                QKhi[(size_t)(rbase + j) * 4096 + col] = h;
                QKlo[(size_t)(rbase + j) * 2048 + col] = l;
            }
        }
    }
}

// ---------------------------------------------------------------------------
// GEMM-KV: [4096 x 2048] x [2048 x 4096] (K,V cols), single bf16 pass.
// ---------------------------------------------------------------------------
__global__ __launch_bounds__(256) void gemm_kv(
    const short* __restrict__ Zhi,
    const short* __restrict__ Bqh,
    short* __restrict__ QKhi,
    short* __restrict__ Vtr, short* __restrict__ Vti)
{
    __shared__ __align__(16) short Ah[128][40], Bh[128][40];
    const int tid = threadIdx.x;
    const int lane = tid & 63, wid = tid >> 6;
    const int c = lane & 15, g = lane >> 4;
    const int wr = wid >> 1, wc = wid & 1;
    const int nt = blockIdx.x, mt = blockIdx.y;
    const int m0 = mt * 128, n0 = 2048 + nt * 128;

    const f4v zero4 = {0.f, 0.f, 0.f, 0.f};
    f4v acc[4][4];
#pragma unroll
    for (int mi = 0; mi < 4; ++mi)
#pragma unroll
        for (int ni = 0; ni < 4; ++ni) acc[mi][ni] = zero4;

    const int r2 = tid >> 2;            // 0..63
    const int koff = (tid & 3) * 8;     // 0,8,16,24

    for (int kt = 0; kt < 64; ++kt) {
        const int k0 = kt * 32;
        __syncthreads();
#pragma unroll
        for (int half = 0; half < 2; ++half) {
            int row = half * 64 + r2;
            size_t ga = (size_t)(m0 + row) * 2048 + k0 + koff;
            size_t gb = (size_t)(n0 + row) * 2048 + k0 + koff;
            *reinterpret_cast<s8v*>(&Ah[row][koff]) = *reinterpret_cast<const s8v*>(&Zhi[ga]);
            *reinterpret_cast<s8v*>(&Bh[row][koff]) = *reinterpret_cast<const s8v*>(&Bqh[gb]);
        }
        __syncthreads();

        s8v ah[4], bh[4];
#pragma unroll
        for (int i = 0; i < 4; ++i) {
            ah[i] = *reinterpret_cast<const s8v*>(&Ah[wr * 64 + i * 16 + c][8 * g]);
            bh[i] = *reinterpret_cast<const s8v*>(&Bh[wc * 64 + i * 16 + c][8 * g]);
        }
        __builtin_amdgcn_s_setprio(1);
#pragma unroll
        for (int mi = 0; mi < 4; ++mi)
#pragma unroll
            for (int ni = 0; ni < 4; ++ni)
                acc[mi][ni] = mf(ah[mi], bh[ni], acc[mi][ni]);
        __builtin_amdgcn_s_setprio(0);
    }

    // epilogue: K cols -> QKhi; V cols -> V^T
#pragma unroll
    for (int mi = 0; mi < 4; ++mi) {
#pragma unroll
        for (int ni = 0; ni < 4; ++ni) {
            int col = n0 + wc * 64 + ni * 16 + c;
            int rbase = m0 + wr * 64 + mi * 16 + 4 * g;
            if (col < 4096) {
#pragma unroll
                for (int j = 0; j < 4; ++j)
                    QKhi[(size_t)(rbase + j) * 4096 + col] = bf16_of(acc[mi][ni][j]);
            } else {
                int cc = col - 4096;
                int part = cc >> 10, o = cc & 1023;
                int hh = o >> 6, d = o & 63;
                int bb = rbase >> 11, s = rbase & 2047;
                short* vt = part ? Vti : Vtr;
                ushort4 pk;
                pk.x = (unsigned short)bf16_of(acc[mi][ni][0]);
                pk.y = (unsigned short)bf16_of(acc[mi][ni][1]);
                pk.z = (unsigned short)bf16_of(acc[mi][ni][2]);
                pk.w = (unsigned short)bf16_of(acc[mi][ni][3]);
                *reinterpret_cast<ushort4*>(&vt[((size_t)(bb * 16 + hh) * 64 + d) * 2048 + s]) = pk;
            }
        }
    }
}

// ---------------------------------------------------------------------------
// Split-K flash attention, KVBLK=32 (was 64): kbuf 16 KB + p_lds 5 KB ->
// 21.5 KB LDS -> 7 blocks/CU (was 4) for latency hiding. 2-phase pipeline
// (stage tile kt+1 under compute of kt, barrier per kt). Swapped QK^T
// (mfma(K,Q)): lane's scores on one query row q=c -> packed cvt_pk P-writes,
// scalar row-sum. Flattened softmax (scores in [0,44.2], no max-sub).
// p_lds row stride 40 shorts (5 bank-quads) -> conflict-free, no XOR.
// ---------------------------------------------------------------------------
__global__ __launch_bounds__(256) void attn_split(
    const short* __restrict__ QKhi, const short* __restrict__ QKlo,
    const short* __restrict__ Vtr, const short* __restrict__ Vti,
    float* __restrict__ Opart, float* __restrict__ Lp)
{
    __shared__ short kbuf[2][32][128];                 // 16 KB, XOR-swizzled 16B slots
    __shared__ __align__(16) short p_lds[4][16][40];   // 5 KB per-wave P tiles
    const int tid = threadIdx.x, lane = tid & 63, wid = tid >> 6;
    const int c = lane & 15, g = lane >> 4;

    const int L = blockIdx.x;
    const int p = (L & 7) + ((L >> 9) << 3);     // (b,h) pair 0..31 (4 per XCD)
    const int j64 = (L >> 3) & 63;
    const int qt = j64 & 31;
    const int half = j64 >> 5;
    const int h = p & 15, b = p >> 4;
    const int kb0 = half * 1024;                 // first key of this block's range

    const int q0 = qt * 64 + wid * 16;
    const int mq = b * 2048 + q0 + c;

    s8v qrh[2], qrl[2], qih[2], qil[2], nqrh[2], nqrl[2];
#pragma unroll
    for (int ks = 0; ks < 2; ++ks) {
        int colr = h * 64 + ks * 32 + 8 * g;
        qrh[ks] = *reinterpret_cast<const s8v*>(&QKhi[(size_t)mq * 4096 + colr]);
        qrl[ks] = *reinterpret_cast<const s8v*>(&QKlo[(size_t)mq * 2048 + colr]);
        qih[ks] = *reinterpret_cast<const s8v*>(&QKhi[(size_t)mq * 4096 + 1024 + colr]);
        qil[ks] = *reinterpret_cast<const s8v*>(&QKlo[(size_t)mq * 2048 + 1024 + colr]);
        nqrh[ks] = qrh[ks] ^ (short)0x8000;
        nqrl[ks] = qrl[ks] ^ (short)0x8000;
    }

    // K staging: LDS row r holds key kb0+kt*32+r; 16B slot s holds logical
    // slot s^(r&7); logical 0..7 = kr d[0..63], 8..15 = ki.
    const int srow = tid >> 4;                 // 0..15
    const int sslot = tid & 15;
    const int slot_u = sslot ^ (srow & 7);
    const int gcol = 2048 + (slot_u >> 3) * 1024 + h * 64 + (slot_u & 7) * 8;
    const short* gK = QKhi + (size_t)(b * 2048) * 4096 + gcol;

    const f4v zero4 = {0.f, 0.f, 0.f, 0.f};
    f4v aor[4], aoi[4];
#pragma unroll
    for (int dt = 0; dt < 4; ++dt) { aor[dt] = zero4; aoi[dt] = zero4; }
    float lrun = 0.f;        // all of this lane's scores belong to q = q0 + c

    // exp(s*0.125) == exp2(s*0.125*log2e)
    const float ESC = 0.125f * 1.44269504f;

    // prologue: stage tile 0
#pragma unroll
    for (int i = 0; i < 2; ++i)
        __builtin_amdgcn_global_load_lds(
            gK + (size_t)(kb0 + i * 16 + srow) * 4096,
            &kbuf[0][i * 16 + wid * 4][0], 16, 0, 0);
    __syncthreads();

    for (int kt = 0; kt < 32; ++kt) {
        const int buf = kt & 1;
        if (kt + 1 < 32) {
#pragma unroll
            for (int i = 0; i < 2; ++i)
                __builtin_amdgcn_global_load_lds(
                    gK + (size_t)(kb0 + (kt + 1) * 32 + i * 16 + srow) * 4096,
                    &kbuf[buf ^ 1][i * 16 + wid * 4][0], 16, 0, 0);
        }

#pragma unroll
        for (int kn = 0; kn < 2; ++kn) {
            f4v sr = zero4, si = zero4;
            const int row = kn * 16 + c;
#pragma unroll
            for (int ks = 0; ks < 2; ++ks) {
                const int sl = (((ks * 4 + g) ^ (c & 7))) * 8;
                s8v krh = *reinterpret_cast<const s8v*>(&kbuf[buf][row][sl]);
                s8v kih = *reinterpret_cast<const s8v*>(&kbuf[buf][row][sl + 64]);
                // swapped operands: lane(c,g) reg j = S[q=c][k=kn*16+4g+j]
                sr = mf(krh, qrh[ks], sr); sr = mf(krh, qrl[ks], sr);
                sr = mf(kih, qih[ks], sr); sr = mf(kih, qil[ks], sr);
                si = mf(krh, qih[ks], si); si = mf(krh, qil[ks], si);
                si = mf(kih, nqrh[ks], si); si = mf(kih, nqrl[ks], si);
            }
            float pv0, pv1, pv2, pv3;
            {
                float a, e;
                a = sr[0]; e = si[0]; pv0 = exp2f(sqrtf(__builtin_fmaf(e, e, a * a)) * ESC);
                a = sr[1]; e = si[1]; pv1 = exp2f(sqrtf(__builtin_fmaf(e, e, a * a)) * ESC);
                a = sr[2]; e = si[2]; pv2 = exp2f(sqrtf(__builtin_fmaf(e, e, a * a)) * ESC);
                a = sr[3]; e = si[3]; pv3 = exp2f(sqrtf(__builtin_fmaf(e, e, a * a)) * ESC);
            }
            lrun += (pv0 + pv1) + (pv2 + pv3);
            unsigned lo32, hi32;
            asm("v_cvt_pk_bf16_f32 %0, %1, %2" : "=v"(lo32) : "v"(pv0), "v"(pv1));
            asm("v_cvt_pk_bf16_f32 %0, %1, %2" : "=v"(hi32) : "v"(pv2), "v"(pv3));
            uint2 pk2; pk2.x = lo32; pk2.y = hi32;
            *reinterpret_cast<uint2*>(&p_lds[wid][c][kn * 16 + 4 * g]) = pk2;
        }

        // PV: P is [16q x 32k] per wave; single K=32 MFMA step
        const size_t vbase = (size_t)((b * 16 + h) * 64) * 2048 + kb0 + kt * 32;
        s8v pa = *reinterpret_cast<const s8v*>(&p_lds[wid][c][8 * g]);
#pragma unroll
        for (int dt = 0; dt < 4; ++dt) {
            size_t va = vbase + (size_t)(dt * 16 + c) * 2048 + 8 * g;
            s8v vr = *reinterpret_cast<const s8v*>(&Vtr[va]);
            s8v vi = *reinterpret_cast<const s8v*>(&Vti[va]);
            aor[dt] = mf(pa, vr, aor[dt]);
            aoi[dt] = mf(pa, vi, aoi[dt]);
        }
        __syncthreads();   // kbuf[buf] free; next tile staged
    }

    // row-sum: lanes c, c+16, c+32, c+48 share q = q0 + c
    {
        float r = lrun;
        r += __shfl_xor(r, 16);
        r += __shfl_xor(r, 32);
        if (g == 0)
            Lp[(size_t)half * 65536 + ((b * 16 + h) << 11) + q0 + c] = r;
    }
    // partial O (fp32) -> Opart
#pragma unroll
    for (int dt = 0; dt < 4; ++dt) {
#pragma unroll
        for (int j = 0; j < 4; ++j) {
            int row = b * 2048 + q0 + 4 * g + j;
            size_t base = ((size_t)half * 4096 + row) * 2048 + h * 64 + dt * 16 + c;
            Opart[base] = aor[dt][j];
            Opart[base + 1024] = aoi[dt][j];
        }
    }
}

// ---------------------------------------------------------------------------
// Combine split-K partials: aout = (O0 + O1) / (l0 + l1), bf16.
// ---------------------------------------------------------------------------
__global__ __launch_bounds__(256) void combine(
    const float* __restrict__ Opart, const float* __restrict__ Lp,
    short* __restrict__ aout)
{
    int idx = blockIdx.x * 256 + threadIdx.x;     // 0 .. 1048575
    int r = idx >> 8, cg = idx & 255;
    int col = cg * 8;
    int b = r >> 11, q = r & 2047;
    int h = (col & 1023) >> 6;
    int lidx = ((b * 16 + h) << 11) + q;
    float li = 1.f / (Lp[lidx] + Lp[65536 + lidx]);
    size_t o0 = (size_t)r * 2048 + col;
    float4 a0 = *reinterpret_cast<const float4*>(Opart + o0);
    float4 a1 = *reinterpret_cast<const float4*>(Opart + o0 + 4);
    float4 b0 = *reinterpret_cast<const float4*>(Opart + 8388608 + o0);
    float4 b1 = *reinterpret_cast<const float4*>(Opart + 8388608 + o0 + 4);
    s8v u;
    u[0] = bf16_of((a0.x + b0.x) * li);
    u[1] = bf16_of((a0.y + b0.y) * li);
    u[2] = bf16_of((a0.z + b0.z) * li);
    u[3] = bf16_of((a0.w + b0.w) * li);
    u[4] = bf16_of((a1.x + b1.x) * li);
    u[5] = bf16_of((a1.y + b1.y) * li);
    u[6] = bf16_of((a1.z + b1.z) * li);
    u[7] = bf16_of((a1.w + b1.w) * li);
    *reinterpret_cast<s8v*>(&aout[o0]) = u;
}

// ---------------------------------------------------------------------------
// GEMM2: attn_out [4096 x 2048] x packed o_w bf16 [2048 x 2048] -> yr|yi fp32
// ---------------------------------------------------------------------------
__global__ __launch_bounds__(256) void gemm_out(
    const short* __restrict__ A,
    const short* __restrict__ Boh,
    float* __restrict__ out)
{
    __shared__ __align__(16) short Ah[128][40], Bh[128][40];
    const int tid = threadIdx.x;
    const int lane = tid & 63, wid = tid >> 6;
    const int c = lane & 15, g = lane >> 4;
    const int wr = wid >> 1, wc = wid & 1;
    const int nt = blockIdx.x, mt = blockIdx.y;
    const int m0 = mt * 128, n0 = nt * 128;

    const f4v zero4 = {0.f, 0.f, 0.f, 0.f};
    f4v acc[4][4];
#pragma unroll
    for (int mi = 0; mi < 4; ++mi)
#pragma unroll
        for (int ni = 0; ni < 4; ++ni) acc[mi][ni] = zero4;

    const int r2 = tid >> 2;
    const int koff = (tid & 3) * 8;

    for (int kt = 0; kt < 64; ++kt) {
        const int k0 = kt * 32;
        __syncthreads();
#pragma unroll
        for (int half = 0; half < 2; ++half) {
            int row = half * 64 + r2;
            *reinterpret_cast<s8v*>(&Ah[row][koff]) =
                *reinterpret_cast<const s8v*>(&A[(size_t)(m0 + row) * 2048 + k0 + koff]);
            *reinterpret_cast<s8v*>(&Bh[row][koff]) =
                *reinterpret_cast<const s8v*>(&Boh[(size_t)(n0 + row) * 2048 + k0 + koff]);
        }
        __syncthreads();

        s8v af[4], bfr[4];
#pragma unroll
        for (int i = 0; i < 4; ++i) {
            af[i]  = *reinterpret_cast<const s8v*>(&Ah[wr * 64 + i * 16 + c][8 * g]);
            bfr[i] = *reinterpret_cast<const s8v*>(&Bh[wc * 64 + i * 16 + c][8 * g]);
        }
        __builtin_amdgcn_s_setprio(1);
#pragma unroll
        for (int mi = 0; mi < 4; ++mi)
#pragma unroll
            for (int ni = 0; ni < 4; ++ni)
                acc[mi][ni] = mf(af[mi], bfr[ni], acc[mi][ni]);
        __builtin_amdgcn_s_setprio(0);
    }

#pragma unroll
    for (int mi = 0; mi < 4; ++mi)
#pragma unroll
        for (int ni = 0; ni < 4; ++ni) {
            int col = n0 + wc * 64 + ni * 16 + c;
#pragma unroll
            for (int j = 0; j < 4; ++j) {
                int row = m0 + wr * 64 + mi * 16 + 4 * g + j;
                float v = acc[mi][ni][j];
                if (col < 1024) out[(size_t)row * 1024 + col] = v;
                else out[4194304 + (size_t)row * 1024 + (col - 1024)] = v;
            }
        }
}

extern "C" void kernel_launch(void* const* d_in, const int* in_sizes, int n_in,
                              void* d_out, int out_size, void* d_ws, size_t ws_size,
                              hipStream_t stream) {
    const float* zr  = (const float*)d_in[0];
    const float* zi  = (const float*)d_in[1];
    const float* qwr = (const float*)d_in[2];
    const float* qwi = (const float*)d_in[3];
    const float* kwr = (const float*)d_in[4];
    const float* kwi = (const float*)d_in[5];
    const float* vwr = (const float*)d_in[6];
    const float* vwi = (const float*)d_in[7];
    const float* owr = (const float*)d_in[8];
    const float* owi = (const float*)d_in[9];

    char* ws = (char*)d_ws;
    short* QKhi = (short*)(ws);                      // 33554432 B
    short* QKlo = (short*)(ws + 33554432);           // 16777216 B (Q cols only)
    short* Vtr  = (short*)(ws + 50331648);           //  8388608 B
    short* Vti  = (short*)(ws + 58720256);           //  8388608 B
    short* aout = (short*)(ws + 67108864);           // 16777216 B
    short* Zhi  = (short*)(ws + 83886080);           // 16777216 B
    short* Zlo  = (short*)(ws + 100663296);          // 16777216 B
    short* Bqh  = (short*)(ws + 117440512);          // 25165824 B
    short* Bql  = (short*)(ws + 142606336);          // 25165824 B
    short* Boh  = (short*)(ws + 167772160);          //  8388608 B  (total 176160768)
    // split-K partials alias the prep buffers (dead after gemm_q/gemm_kv):
    float* Opart = (float*)(ws + 83886080);          // 67108864 B over Zhi..Bqh(+)
    float* Lp    = (float*)(ws + 150994944);         //   524288 B inside Bql

    prep_z<<<dim3(8192), 256, 0, stream>>>(zr, zi, Zhi, Zlo);
    prep_wqkv<<<dim3(12288), 256, 0, stream>>>(qwr, qwi, kwr, kwi, vwr, vwi, Bqh, Bql);
    prep_wo<<<dim3(4096), 256, 0, stream>>>(owr, owi, Boh);
    gemm_q<<<dim3(16, 32, 1), 256, 0, stream>>>(Zhi, Zlo, Bqh, Bql, QKhi, QKlo);
    gemm_kv<<<dim3(32, 32, 1), 256, 0, stream>>>(Zhi, Bqh, QKhi, Vtr, Vti);
    attn_split<<<dim3(2048), 256, 0, stream>>>(QKhi, QKlo, Vtr, Vti, Opart, Lp);
    combine<<<dim3(4096), 256, 0, stream>>>(Opart, Lp, aout);
    gemm_out<<<dim3(16, 32, 1), 256, 0, stream>>>(aout, Boh, (float*)d_out);
}

// Round 11
// 526.351 us; speedup vs baseline: 1.4392x; 1.1595x over previous
//
#include <hip/hip_runtime.h>
#include <hip/hip_bf16.h>
#include <cmath>

typedef __attribute__((ext_vector_type(8))) short s8v;   // 8 bf16 (4 VGPR) MFMA operand / 16B chunk
typedef __attribute__((ext_vector_type(4))) float f4v;   // MFMA accumulator

__device__ __forceinline__ f4v mf(s8v a, s8v b, f4v c) {
    return __builtin_amdgcn_mfma_f32_16x16x32_bf16(a, b, c, 0, 0, 0);
}

// RNE float -> bf16 bits (finite inputs only)
__device__ __forceinline__ short bf16_of(float f) {
    unsigned u = __builtin_bit_cast(unsigned, f);
    unsigned r = (u + 0x7FFFu + ((u >> 16) & 1u)) >> 16;
    return (short)r;
}
__device__ __forceinline__ float f_of_bf16(short h) {
    return __builtin_bit_cast(float, ((unsigned)(unsigned short)h) << 16);
}
__device__ __forceinline__ void split2(float v, short& h, short& l) {
    short hh = bf16_of(v);
    h = hh;
    l = bf16_of(v - f_of_bf16(hh));
}

// ---------------------------------------------------------------------------
// Prep 1: z (zr|zi fp32 [4096][1024] each) -> Zhi/Zlo bf16 [4096][2048]
// ---------------------------------------------------------------------------
__global__ __launch_bounds__(256) void prep_z(
    const float* __restrict__ zr, const float* __restrict__ zi,
    short* __restrict__ Zhi, short* __restrict__ Zlo)
{
    int idx = blockIdx.x * 256 + threadIdx.x;        // 0 .. 4096*512-1
    int m = idx >> 9, kq = idx & 511;                // kq = float4 index in 2048-col row
    const float* src = (kq < 256) ? (zr + (size_t)m * 1024 + kq * 4)
                                  : (zi + (size_t)m * 1024 + (kq - 256) * 4);
    float4 v = *reinterpret_cast<const float4*>(src);
    ushort4 hi, lo;
    short h, l;
    split2(v.x, h, l); hi.x = h; lo.x = l;
    split2(v.y, h, l); hi.y = h; lo.y = l;
    split2(v.z, h, l); hi.z = h; lo.z = l;
    split2(v.w, h, l); hi.w = h; lo.w = l;
    *reinterpret_cast<ushort4*>(&Zhi[(size_t)m * 2048 + kq * 4]) = hi;
    *reinterpret_cast<ushort4*>(&Zlo[(size_t)m * 2048 + kq * 4]) = lo;
}

// ---------------------------------------------------------------------------
// Prep 2: q/k/v weights -> packed B [6144][2048] hi/lo bf16 (signs baked).
// ---------------------------------------------------------------------------
__global__ __launch_bounds__(256) void prep_wqkv(
    const float* __restrict__ qwr, const float* __restrict__ qwi,
    const float* __restrict__ kwr, const float* __restrict__ kwi,
    const float* __restrict__ vwr, const float* __restrict__ vwi,
    short* __restrict__ Bqh, short* __restrict__ Bql)
{
    int idx = blockIdx.x * 256 + threadIdx.x;        // 0 .. 6144*512-1
    int n = idx >> 9, kq = idx & 511;
    int k = kq * 4;
    int t = n >> 11, cpart = (n >> 10) & 1, o = n & 1023;
    const float* Wr = (t == 0) ? qwr : (t == 1) ? kwr : vwr;
    const float* Wi = (t == 0) ? qwi : (t == 1) ? kwi : vwi;
    const float* W;
    float sgn;
    int kk;
    if (k < 1024) { W = cpart ? Wi : Wr; sgn = 1.f; kk = k; }
    else          { W = cpart ? Wr : Wi; sgn = cpart ? 1.f : -1.f; kk = k - 1024; }
    float4 v = *reinterpret_cast<const float4*>(W + (size_t)o * 1024 + kk);
    ushort4 hi, lo;
    short h, l;
    split2(sgn * v.x, h, l); hi.x = h; lo.x = l;
    split2(sgn * v.y, h, l); hi.y = h; lo.y = l;
    split2(sgn * v.z, h, l); hi.z = h; lo.z = l;
    split2(sgn * v.w, h, l); hi.w = h; lo.w = l;
    *reinterpret_cast<ushort4*>(&Bqh[(size_t)n * 2048 + k]) = hi;
    *reinterpret_cast<ushort4*>(&Bql[(size_t)n * 2048 + k]) = lo;
}

// ---------------------------------------------------------------------------
// Prep 3: o weights -> packed Bo [2048][2048] bf16 (hi only, signs baked)
// ---------------------------------------------------------------------------
__global__ __launch_bounds__(256) void prep_wo(
    const float* __restrict__ owr, const float* __restrict__ owi,
    short* __restrict__ Boh)
{
    int idx = blockIdx.x * 256 + threadIdx.x;        // 0 .. 2048*512-1
    int n = idx >> 9, kq = idx & 511;
    int k = kq * 4;
    int part = n >> 10, o = n & 1023;
    const float* W;
    float sgn;
    int kk;
    if (k < 1024) { W = part ? owi : owr; sgn = 1.f; kk = k; }
    else          { W = part ? owr : owi; sgn = part ? 1.f : -1.f; kk = k - 1024; }
    float4 v = *reinterpret_cast<const float4*>(W + (size_t)o * 1024 + kk);
    ushort4 hi;
    hi.x = (unsigned short)bf16_of(sgn * v.x);
    hi.y = (unsigned short)bf16_of(sgn * v.y);
    hi.z = (unsigned short)bf16_of(sgn * v.z);
    hi.w = (unsigned short)bf16_of(sgn * v.w);
    *reinterpret_cast<ushort4*>(&Boh[(size_t)n * 2048 + k]) = hi;
}

// ---------------------------------------------------------------------------
// GEMM-Q: [4096 x 2048] x [2048 x 2048] (Q cols only), 3-pass bf16 split.
// ---------------------------------------------------------------------------
__global__ __launch_bounds__(256) void gemm_q(
    const short* __restrict__ Zhi, const short* __restrict__ Zlo,
    const short* __restrict__ Bqh, const short* __restrict__ Bql,
    short* __restrict__ QKhi, short* __restrict__ QKlo)
{
    __shared__ __align__(16) short Ah[128][40], Al[128][40], Bh[128][40], Bl[128][40];
    const int tid = threadIdx.x;
    const int lane = tid & 63, wid = tid >> 6;
    const int c = lane & 15, g = lane >> 4;
    const int wr = wid >> 1, wc = wid & 1;
    const int nt = blockIdx.x, mt = blockIdx.y;
    const int m0 = mt * 128, n0 = nt * 128;

    const f4v zero4 = {0.f, 0.f, 0.f, 0.f};
    f4v acc[4][4];
#pragma unroll
    for (int mi = 0; mi < 4; ++mi)
#pragma unroll
        for (int ni = 0; ni < 4; ++ni) acc[mi][ni] = zero4;

    const int r2 = tid >> 2;            // 0..63
    const int koff = (tid & 3) * 8;     // 0,8,16,24

    for (int kt = 0; kt < 64; ++kt) {
        const int k0 = kt * 32;
        __syncthreads();
#pragma unroll
        for (int half = 0; half < 2; ++half) {
            int row = half * 64 + r2;
            size_t ga = (size_t)(m0 + row) * 2048 + k0 + koff;
            size_t gb = (size_t)(n0 + row) * 2048 + k0 + koff;
            *reinterpret_cast<s8v*>(&Ah[row][koff]) = *reinterpret_cast<const s8v*>(&Zhi[ga]);
            *reinterpret_cast<s8v*>(&Al[row][koff]) = *reinterpret_cast<const s8v*>(&Zlo[ga]);
            *reinterpret_cast<s8v*>(&Bh[row][koff]) = *reinterpret_cast<const s8v*>(&Bqh[gb]);
            *reinterpret_cast<s8v*>(&Bl[row][koff]) = *reinterpret_cast<const s8v*>(&Bql[gb]);
        }
        __syncthreads();

        s8v ah[4], alo[4], bh[4], blo[4];
#pragma unroll
        for (int i = 0; i < 4; ++i) {
            ah[i]  = *reinterpret_cast<const s8v*>(&Ah[wr * 64 + i * 16 + c][8 * g]);
            alo[i] = *reinterpret_cast<const s8v*>(&Al[wr * 64 + i * 16 + c][8 * g]);
            bh[i]  = *reinterpret_cast<const s8v*>(&Bh[wc * 64 + i * 16 + c][8 * g]);
            blo[i] = *reinterpret_cast<const s8v*>(&Bl[wc * 64 + i * 16 + c][8 * g]);
        }
        __builtin_amdgcn_s_setprio(1);
#pragma unroll
        for (int mi = 0; mi < 4; ++mi)
#pragma unroll
            for (int ni = 0; ni < 4; ++ni) {
                acc[mi][ni] = mf(ah[mi], bh[ni], acc[mi][ni]);
                acc[mi][ni] = mf(ah[mi], blo[ni], acc[mi][ni]);
                acc[mi][ni] = mf(alo[mi], bh[ni], acc[mi][ni]);
            }
        __builtin_amdgcn_s_setprio(0);
    }

    // epilogue: cols all < 2048 -> Q hi + lo
#pragma unroll
    for (int mi = 0; mi < 4; ++mi) {
#pragma unroll
        for (int ni = 0; ni < 4; ++ni) {
            int col = n0 + wc * 64 + ni * 16 + c;
            int rbase = m0 + wr * 64 + mi * 16 + 4 * g;
#pragma unroll
            for (int j = 0; j < 4; ++j) {
                short h, l;
                split2(acc[mi][ni][j], h, l);
                QKhi[(size_t)(rbase + j) * 4096 + col] = h;
                QKlo[(size_t)(rbase + j) * 2048 + col] = l;
            }
        }
    }
}

// ---------------------------------------------------------------------------
// GEMM-KV: [4096 x 2048] x [2048 x 4096] (K,V cols), single bf16 pass.
// ---------------------------------------------------------------------------
__global__ __launch_bounds__(256) void gemm_kv(
    const short* __restrict__ Zhi,
    const short* __restrict__ Bqh,
    short* __restrict__ QKhi,
    short* __restrict__ Vtr, short* __restrict__ Vti)
{
    __shared__ __align__(16) short Ah[128][40], Bh[128][40];
    const int tid = threadIdx.x;
    const int lane = tid & 63, wid = tid >> 6;
    const int c = lane & 15, g = lane >> 4;
    const int wr = wid >> 1, wc = wid & 1;
    const int nt = blockIdx.x, mt = blockIdx.y;
    const int m0 = mt * 128, n0 = 2048 + nt * 128;

    const f4v zero4 = {0.f, 0.f, 0.f, 0.f};
    f4v acc[4][4];
#pragma unroll
    for (int mi = 0; mi < 4; ++mi)
#pragma unroll
        for (int ni = 0; ni < 4; ++ni) acc[mi][ni] = zero4;

    const int r2 = tid >> 2;            // 0..63
    const int koff = (tid & 3) * 8;     // 0,8,16,24

    for (int kt = 0; kt < 64; ++kt) {
        const int k0 = kt * 32;
        __syncthreads();
#pragma unroll
        for (int half = 0; half < 2; ++half) {
            int row = half * 64 + r2;
            size_t ga = (size_t)(m0 + row) * 2048 + k0 + koff;
            size_t gb = (size_t)(n0 + row) * 2048 + k0 + koff;
            *reinterpret_cast<s8v*>(&Ah[row][koff]) = *reinterpret_cast<const s8v*>(&Zhi[ga]);
            *reinterpret_cast<s8v*>(&Bh[row][koff]) = *reinterpret_cast<const s8v*>(&Bqh[gb]);
        }
        __syncthreads();

        s8v ah[4], bh[4];
#pragma unroll
        for (int i = 0; i < 4; ++i) {
            ah[i] = *reinterpret_cast<const s8v*>(&Ah[wr * 64 + i * 16 + c][8 * g]);
            bh[i] = *reinterpret_cast<const s8v*>(&Bh[wc * 64 + i * 16 + c][8 * g]);
        }
        __builtin_amdgcn_s_setprio(1);
#pragma unroll
        for (int mi = 0; mi < 4; ++mi)
#pragma unroll
            for (int ni = 0; ni < 4; ++ni)
                acc[mi][ni] = mf(ah[mi], bh[ni], acc[mi][ni]);
        __builtin_amdgcn_s_setprio(0);
    }

    // epilogue: K cols -> QKhi; V cols -> V^T
#pragma unroll
    for (int mi = 0; mi < 4; ++mi) {
#pragma unroll
        for (int ni = 0; ni < 4; ++ni) {
            int col = n0 + wc * 64 + ni * 16 + c;
            int rbase = m0 + wr * 64 + mi * 16 + 4 * g;
            if (col < 4096) {
#pragma unroll
                for (int j = 0; j < 4; ++j)
                    QKhi[(size_t)(rbase + j) * 4096 + col] = bf16_of(acc[mi][ni][j]);
            } else {
                int cc = col - 4096;
                int part = cc >> 10, o = cc & 1023;
                int hh = o >> 6, d = o & 63;
                int bb = rbase >> 11, s = rbase & 2047;
                short* vt = part ? Vti : Vtr;
                ushort4 pk;
                pk.x = (unsigned short)bf16_of(acc[mi][ni][0]);
                pk.y = (unsigned short)bf16_of(acc[mi][ni][1]);
                pk.z = (unsigned short)bf16_of(acc[mi][ni][2]);
                pk.w = (unsigned short)bf16_of(acc[mi][ni][3]);
                *reinterpret_cast<ushort4*>(&vt[((size_t)(bb * 16 + hh) * 64 + d) * 2048 + s]) = pk;
            }
        }
    }
}

// ---------------------------------------------------------------------------
// Split-K flash attention, TA-instruction-minimized: K AND V both staged in
// LDS once per block (V was previously loaded redundantly by all 4 waves
// direct from global -> 8 extra VMEM instrs/wave/kt; rounds 7/8/10 durations
// track VMEM instr count). Global instrs now 4/wave/kt (2 K-stage + 2 V-stage).
// vbuf rows = d (128B: vr 64B | vi 64B), XOR-swizzled 16B slots via
// pre-swizzled per-lane global source + swizzled ds_read (rule 21).
// Swapped QK^T, flattened softmax, split-K x2, KVBLK=32.
// ---------------------------------------------------------------------------
__global__ __launch_bounds__(256) void attn_split(
    const short* __restrict__ QKhi, const short* __restrict__ QKlo,
    const short* __restrict__ Vtr, const short* __restrict__ Vti,
    float* __restrict__ Opart, float* __restrict__ Lp)
{
    __shared__ short kbuf[2][32][128];                 // 16 KB: row=key, [kr|ki], XOR slots
    __shared__ short vbuf[2][64][64];                  // 16 KB: row=d, [vr 32k|vi 32k], XOR slots
    __shared__ __align__(16) short p_lds[4][16][40];   // 5 KB per-wave P tiles
    const int tid = threadIdx.x, lane = tid & 63, wid = tid >> 6;
    const int c = lane & 15, g = lane >> 4;

    const int L = blockIdx.x;
    const int p = (L & 7) + ((L >> 9) << 3);     // (b,h) pair 0..31 (4 per XCD)
    const int j64 = (L >> 3) & 63;
    const int qt = j64 & 31;
    const int half = j64 >> 5;
    const int h = p & 15, b = p >> 4;
    const int kb0 = half * 1024;                 // first key of this block's range

    const int q0 = qt * 64 + wid * 16;
    const int mq = b * 2048 + q0 + c;

    s8v qrh[2], qrl[2], qih[2], qil[2], nqrh[2], nqrl[2];
#pragma unroll
    for (int ks = 0; ks < 2; ++ks) {
        int colr = h * 64 + ks * 32 + 8 * g;
        qrh[ks] = *reinterpret_cast<const s8v*>(&QKhi[(size_t)mq * 4096 + colr]);
        qrl[ks] = *reinterpret_cast<const s8v*>(&QKlo[(size_t)mq * 2048 + colr]);
        qih[ks] = *reinterpret_cast<const s8v*>(&QKhi[(size_t)mq * 4096 + 1024 + colr]);
        qil[ks] = *reinterpret_cast<const s8v*>(&QKlo[(size_t)mq * 2048 + 1024 + colr]);
        nqrh[ks] = qrh[ks] ^ (short)0x8000;
        nqrl[ks] = qrl[ks] ^ (short)0x8000;
    }

    // K staging: LDS row r holds key; physical 16B slot s holds logical
    // u = s^(r&7); u 0..7 = kr d[0..63], 8..15 = ki.
    const int srow = tid >> 4;                 // 0..15
    const int sslot = tid & 15;
    const int kslot_u = sslot ^ (srow & 7);
    const int gcolK = 2048 + (kslot_u >> 3) * 1024 + h * 64 + (kslot_u & 7) * 8;
    const short* gK = QKhi + (size_t)(b * 2048) * 4096 + gcolK;

    // V staging: vbuf row = d (0..63); physical slot s (0..7) holds logical
    // u = s^(d&7); u 0..3 = vr keys [8u..8u+7], u 4..7 = vi keys [8(u-4)..].
    // Wave stages rows wid*16+i*8 .. +7 per instr i; lane l -> local row l>>3,
    // physical slot l&7 -> per-lane global source pre-swizzled.
    const int vlr = lane >> 3;                  // local row 0..7
    const int vs = lane & 7;                    // physical slot
    const short* gV[2];
#pragma unroll
    for (int i = 0; i < 2; ++i) {
        int d = wid * 16 + i * 8 + vlr;
        int u = vs ^ (d & 7);
        const short* base = (u < 4) ? Vtr : Vti;
        gV[i] = base + (size_t)((b * 16 + h) * 64 + d) * 2048 + (u & 3) * 8;
    }

    const f4v zero4 = {0.f, 0.f, 0.f, 0.f};
    f4v aor[4], aoi[4];
#pragma unroll
    for (int dt = 0; dt < 4; ++dt) { aor[dt] = zero4; aoi[dt] = zero4; }
    float lrun = 0.f;        // all of this lane's scores belong to q = q0 + c

    // exp(s*0.125) == exp2(s*0.125*log2e)
    const float ESC = 0.125f * 1.44269504f;

    // prologue: stage tile 0 (K + V)
#pragma unroll
    for (int i = 0; i < 2; ++i) {
        __builtin_amdgcn_global_load_lds(
            gK + (size_t)(kb0 + i * 16 + srow) * 4096,
            &kbuf[0][i * 16 + wid * 4][0], 16, 0, 0);
        __builtin_amdgcn_global_load_lds(
            gV[i] + kb0,
            &vbuf[0][wid * 16 + i * 8][0], 16, 0, 0);
    }
    __syncthreads();

    for (int kt = 0; kt < 32; ++kt) {
        const int buf = kt & 1;
        if (kt + 1 < 32) {
            const int ko = kb0 + (kt + 1) * 32;
#pragma unroll
            for (int i = 0; i < 2; ++i) {
                __builtin_amdgcn_global_load_lds(
                    gK + (size_t)(ko + i * 16 + srow) * 4096,
                    &kbuf[buf ^ 1][i * 16 + wid * 4][0], 16, 0, 0);
                __builtin_amdgcn_global_load_lds(
                    gV[i] + ko,
                    &vbuf[buf ^ 1][wid * 16 + i * 8][0], 16, 0, 0);
            }
        }

#pragma unroll
        for (int kn = 0; kn < 2; ++kn) {
            f4v sr = zero4, si = zero4;
            const int row = kn * 16 + c;
#pragma unroll
            for (int ks = 0; ks < 2; ++ks) {
                const int sl = (((ks * 4 + g) ^ (c & 7))) * 8;
                s8v krh = *reinterpret_cast<const s8v*>(&kbuf[buf][row][sl]);
                s8v kih = *reinterpret_cast<const s8v*>(&kbuf[buf][row][sl + 64]);
                // swapped operands: lane(c,g) reg j = S[q=c][k=kn*16+4g+j]
                sr = mf(krh, qrh[ks], sr); sr = mf(krh, qrl[ks], sr);
                sr = mf(kih, qih[ks], sr); sr = mf(kih, qil[ks], sr);
                si = mf(krh, qih[ks], si); si = mf(krh, qil[ks], si);
                si = mf(kih, nqrh[ks], si); si = mf(kih, nqrl[ks], si);
            }
            float pv0, pv1, pv2, pv3;
            {
                float a, e;
                a = sr[0]; e = si[0]; pv0 = exp2f(sqrtf(__builtin_fmaf(e, e, a * a)) * ESC);
                a = sr[1]; e = si[1]; pv1 = exp2f(sqrtf(__builtin_fmaf(e, e, a * a)) * ESC);
                a = sr[2]; e = si[2]; pv2 = exp2f(sqrtf(__builtin_fmaf(e, e, a * a)) * ESC);
                a = sr[3]; e = si[3]; pv3 = exp2f(sqrtf(__builtin_fmaf(e, e, a * a)) * ESC);
            }
            lrun += (pv0 + pv1) + (pv2 + pv3);
            unsigned lo32, hi32;
            asm("v_cvt_pk_bf16_f32 %0, %1, %2" : "=v"(lo32) : "v"(pv0), "v"(pv1));
            asm("v_cvt_pk_bf16_f32 %0, %1, %2" : "=v"(hi32) : "v"(pv2), "v"(pv3));
            uint2 pk2; pk2.x = lo32; pk2.y = hi32;
            *reinterpret_cast<uint2*>(&p_lds[wid][c][kn * 16 + 4 * g]) = pk2;
        }

        // PV: P is [16q x 32k] per wave; V from shared vbuf (swizzled read)
        s8v pa = *reinterpret_cast<const s8v*>(&p_lds[wid][c][8 * g]);
#pragma unroll
        for (int dt = 0; dt < 4; ++dt) {
            const int d = dt * 16 + c;
            const int sr_ = (g ^ (d & 7)) * 8;          // vr logical slot g
            const int si_ = ((4 + g) ^ (d & 7)) * 8;    // vi logical slot 4+g
            s8v vr = *reinterpret_cast<const s8v*>(&vbuf[buf][d][sr_]);
            s8v vi = *reinterpret_cast<const s8v*>(&vbuf[buf][d][si_]);
            aor[dt] = mf(pa, vr, aor[dt]);
            aoi[dt] = mf(pa, vi, aoi[dt]);
        }
        __syncthreads();   // kbuf/vbuf[buf] free; next tile staged
    }

    // row-sum: lanes c, c+16, c+32, c+48 share q = q0 + c
    {
        float r = lrun;
        r += __shfl_xor(r, 16);
        r += __shfl_xor(r, 32);
        if (g == 0)
            Lp[(size_t)half * 65536 + ((b * 16 + h) << 11) + q0 + c] = r;
    }
    // partial O (fp32) -> Opart
#pragma unroll
    for (int dt = 0; dt < 4; ++dt) {
#pragma unroll
        for (int j = 0; j < 4; ++j) {
            int row = b * 2048 + q0 + 4 * g + j;
            size_t base = ((size_t)half * 4096 + row) * 2048 + h * 64 + dt * 16 + c;
            Opart[base] = aor[dt][j];
            Opart[base + 1024] = aoi[dt][j];
        }
    }
}

// ---------------------------------------------------------------------------
// Combine split-K partials: aout = (O0 + O1) / (l0 + l1), bf16.
// ---------------------------------------------------------------------------
__global__ __launch_bounds__(256) void combine(
    const float* __restrict__ Opart, const float* __restrict__ Lp,
    short* __restrict__ aout)
{
    int idx = blockIdx.x * 256 + threadIdx.x;     // 0 .. 1048575
    int r = idx >> 8, cg = idx & 255;
    int col = cg * 8;
    int b = r >> 11, q = r & 2047;
    int h = (col & 1023) >> 6;
    int lidx = ((b * 16 + h) << 11) + q;
    float li = 1.f / (Lp[lidx] + Lp[65536 + lidx]);
    size_t o0 = (size_t)r * 2048 + col;
    float4 a0 = *reinterpret_cast<const float4*>(Opart + o0);
    float4 a1 = *reinterpret_cast<const float4*>(Opart + o0 + 4);
    float4 b0 = *reinterpret_cast<const float4*>(Opart + 8388608 + o0);
    float4 b1 = *reinterpret_cast<const float4*>(Opart + 8388608 + o0 + 4);
    s8v u;
    u[0] = bf16_of((a0.x + b0.x) * li);
    u[1] = bf16_of((a0.y + b0.y) * li);
    u[2] = bf16_of((a0.z + b0.z) * li);
    u[3] = bf16_of((a0.w + b0.w) * li);
    u[4] = bf16_of((a1.x + b1.x) * li);
    u[5] = bf16_of((a1.y + b1.y) * li);
    u[6] = bf16_of((a1.z + b1.z) * li);
    u[7] = bf16_of((a1.w + b1.w) * li);
    *reinterpret_cast<s8v*>(&aout[o0]) = u;
}

// ---------------------------------------------------------------------------
// GEMM2: attn_out [4096 x 2048] x packed o_w bf16 [2048 x 2048] -> yr|yi fp32
// ---------------------------------------------------------------------------
__global__ __launch_bounds__(256) void gemm_out(
    const short* __restrict__ A,
    const short* __restrict__ Boh,
    float* __restrict__ out)
{
    __shared__ __align__(16) short Ah[128][40], Bh[128][40];
    const int tid = threadIdx.x;
    const int lane = tid & 63, wid = tid >> 6;
    const int c = lane & 15, g = lane >> 4;
    const int wr = wid >> 1, wc = wid & 1;
    const int nt = blockIdx.x, mt = blockIdx.y;
    const int m0 = mt * 128, n0 = nt * 128;

    const f4v zero4 = {0.f, 0.f, 0.f, 0.f};
    f4v acc[4][4];
#pragma unroll
    for (int mi = 0; mi < 4; ++mi)
#pragma unroll
        for (int ni = 0; ni < 4; ++ni) acc[mi][ni] = zero4;

    const int r2 = tid >> 2;
    const int koff = (tid & 3) * 8;

    for (int kt = 0; kt < 64; ++kt) {
        const int k0 = kt * 32;
        __syncthreads();
#pragma unroll
        for (int half = 0; half < 2; ++half) {
            int row = half * 64 + r2;
            *reinterpret_cast<s8v*>(&Ah[row][koff]) =
                *reinterpret_cast<const s8v*>(&A[(size_t)(m0 + row) * 2048 + k0 + koff]);
            *reinterpret_cast<s8v*>(&Bh[row][koff]) =
                *reinterpret_cast<const s8v*>(&Boh[(size_t)(n0 + row) * 2048 + k0 + koff]);
        }
        __syncthreads();

        s8v af[4], bfr[4];
#pragma unroll
        for (int i = 0; i < 4; ++i) {
            af[i]  = *reinterpret_cast<const s8v*>(&Ah[wr * 64 + i * 16 + c][8 * g]);
            bfr[i] = *reinterpret_cast<const s8v*>(&Bh[wc * 64 + i * 16 + c][8 * g]);
        }
        __builtin_amdgcn_s_setprio(1);
#pragma unroll
        for (int mi = 0; mi < 4; ++mi)
#pragma unroll
            for (int ni = 0; ni < 4; ++ni)
                acc[mi][ni] = mf(af[mi], bfr[ni], acc[mi][ni]);
        __builtin_amdgcn_s_setprio(0);
    }

#pragma unroll
    for (int mi = 0; mi < 4; ++mi)
#pragma unroll
        for (int ni = 0; ni < 4; ++ni) {
            int col = n0 + wc * 64 + ni * 16 + c;
#pragma unroll
            for (int j = 0; j < 4; ++j) {
                int row = m0 + wr * 64 + mi * 16 + 4 * g + j;
                float v = acc[mi][ni][j];
                if (col < 1024) out[(size_t)row * 1024 + col] = v;
                else out[4194304 + (size_t)row * 1024 + (col - 1024)] = v;
            }
        }
}

extern "C" void kernel_launch(void* const* d_in, const int* in_sizes, int n_in,
                              void* d_out, int out_size, void* d_ws, size_t ws_size,
                              hipStream_t stream) {
    const float* zr  = (const float*)d_in[0];
    const float* zi  = (const float*)d_in[1];
    const float* qwr = (const float*)d_in[2];
    const float* qwi = (const float*)d_in[3];
    const float* kwr = (const float*)d_in[4];
    const float* kwi = (const float*)d_in[5];
    const float* vwr = (const float*)d_in[6];
    const float* vwi = (const float*)d_in[7];
    const float* owr = (const float*)d_in[8];
    const float* owi = (const float*)d_in[9];

    char* ws = (char*)d_ws;
    short* QKhi = (short*)(ws);                      // 33554432 B
    short* QKlo = (short*)(ws + 33554432);           // 16777216 B (Q cols only)
    short* Vtr  = (short*)(ws + 50331648);           //  8388608 B
    short* Vti  = (short*)(ws + 58720256);           //  8388608 B
    short* aout = (short*)(ws + 67108864);           // 16777216 B
    short* Zhi  = (short*)(ws + 83886080);           // 16777216 B
    short* Zlo  = (short*)(ws + 100663296);          // 16777216 B
    short* Bqh  = (short*)(ws + 117440512);          // 25165824 B
    short* Bql  = (short*)(ws + 142606336);          // 25165824 B
    short* Boh  = (short*)(ws + 167772160);          //  8388608 B  (total 176160768)
    // split-K partials alias the prep buffers (dead after gemm_q/gemm_kv):
    float* Opart = (float*)(ws + 83886080);          // 67108864 B over Zhi..Bqh(+)
    float* Lp    = (float*)(ws + 150994944);         //   524288 B inside Bql

    prep_z<<<dim3(8192), 256, 0, stream>>>(zr, zi, Zhi, Zlo);
    prep_wqkv<<<dim3(12288), 256, 0, stream>>>(qwr, qwi, kwr, kwi, vwr, vwi, Bqh, Bql);
    prep_wo<<<dim3(4096), 256, 0, stream>>>(owr, owi, Boh);
    gemm_q<<<dim3(16, 32, 1), 256, 0, stream>>>(Zhi, Zlo, Bqh, Bql, QKhi, QKlo);
    gemm_kv<<<dim3(32, 32, 1), 256, 0, stream>>>(Zhi, Bqh, QKhi, Vtr, Vti);
    attn_split<<<dim3(2048), 256, 0, stream>>>(QKhi, QKlo, Vtr, Vti, Opart, Lp);
    combine<<<dim3(4096), 256, 0, stream>>>(Opart, Lp, aout);
    gemm_out<<<dim3(16, 32, 1), 256, 0, stream>>>(aout, Boh, (float*)d_out);
}

// Round 12
// 480.625 us; speedup vs baseline: 1.5762x; 1.0951x over previous
//
#include <hip/hip_runtime.h>
#include <hip/hip_bf16.h>
#include <cmath>

typedef __attribute__((ext_vector_type(8))) short s8v;   // 8 bf16 (4 VGPR) MFMA operand / 16B chunk
typedef __attribute__((ext_vector_type(4))) float f4v;   // MFMA accumulator

__device__ __forceinline__ f4v mf(s8v a, s8v b, f4v c) {
    return __builtin_amdgcn_mfma_f32_16x16x32_bf16(a, b, c, 0, 0, 0);
}

// RNE float -> bf16 bits (finite inputs only)
__device__ __forceinline__ short bf16_of(float f) {
    unsigned u = __builtin_bit_cast(unsigned, f);
    unsigned r = (u + 0x7FFFu + ((u >> 16) & 1u)) >> 16;
    return (short)r;
}
__device__ __forceinline__ float f_of_bf16(short h) {
    return __builtin_bit_cast(float, ((unsigned)(unsigned short)h) << 16);
}
__device__ __forceinline__ void split2(float v, short& h, short& l) {
    short hh = bf16_of(v);
    h = hh;
    l = bf16_of(v - f_of_bf16(hh));
}

// fast hw sqrt/exp2 (1-ulp; inputs here are normal-range, >= 0)
__device__ __forceinline__ float hw_sqrt(float x) {
    float r;
    asm("v_sqrt_f32 %0, %1" : "=v"(r) : "v"(x));
    return r;
}
__device__ __forceinline__ float hw_exp2(float x) {
    float r;
    asm("v_exp_f32 %0, %1" : "=v"(r) : "v"(x));
    return r;
}

// ---------------------------------------------------------------------------
// Prep 1: z (zr|zi fp32 [4096][1024] each) -> Zhi/Zlo bf16 [4096][2048]
// ---------------------------------------------------------------------------
__global__ __launch_bounds__(256) void prep_z(
    const float* __restrict__ zr, const float* __restrict__ zi,
    short* __restrict__ Zhi, short* __restrict__ Zlo)
{
    int idx = blockIdx.x * 256 + threadIdx.x;        // 0 .. 4096*512-1
    int m = idx >> 9, kq = idx & 511;                // kq = float4 index in 2048-col row
    const float* src = (kq < 256) ? (zr + (size_t)m * 1024 + kq * 4)
                                  : (zi + (size_t)m * 1024 + (kq - 256) * 4);
    float4 v = *reinterpret_cast<const float4*>(src);
    ushort4 hi, lo;
    short h, l;
    split2(v.x, h, l); hi.x = h; lo.x = l;
    split2(v.y, h, l); hi.y = h; lo.y = l;
    split2(v.z, h, l); hi.z = h; lo.z = l;
    split2(v.w, h, l); hi.w = h; lo.w = l;
    *reinterpret_cast<ushort4*>(&Zhi[(size_t)m * 2048 + kq * 4]) = hi;
    *reinterpret_cast<ushort4*>(&Zlo[(size_t)m * 2048 + kq * 4]) = lo;
}

// ---------------------------------------------------------------------------
// Prep 2: q/k/v weights -> packed B [6144][2048] hi/lo bf16 (signs baked).
// ---------------------------------------------------------------------------
__global__ __launch_bounds__(256) void prep_wqkv(
    const float* __restrict__ qwr, const float* __restrict__ qwi,
    const float* __restrict__ kwr, const float* __restrict__ kwi,
    const float* __restrict__ vwr, const float* __restrict__ vwi,
    short* __restrict__ Bqh, short* __restrict__ Bql)
{
    int idx = blockIdx.x * 256 + threadIdx.x;        // 0 .. 6144*512-1
    int n = idx >> 9, kq = idx & 511;
    int k = kq * 4;
    int t = n >> 11, cpart = (n >> 10) & 1, o = n & 1023;
    const float* Wr = (t == 0) ? qwr : (t == 1) ? kwr : vwr;
    const float* Wi = (t == 0) ? qwi : (t == 1) ? kwi : vwi;
    const float* W;
    float sgn;
    int kk;
    if (k < 1024) { W = cpart ? Wi : Wr; sgn = 1.f; kk = k; }
    else          { W = cpart ? Wr : Wi; sgn = cpart ? 1.f : -1.f; kk = k - 1024; }
    float4 v = *reinterpret_cast<const float4*>(W + (size_t)o * 1024 + kk);
    ushort4 hi, lo;
    short h, l;
    split2(sgn * v.x, h, l); hi.x = h; lo.x = l;
    split2(sgn * v.y, h, l); hi.y = h; lo.y = l;
    split2(sgn * v.z, h, l); hi.z = h; lo.z = l;
    split2(sgn * v.w, h, l); hi.w = h; lo.w = l;
    *reinterpret_cast<ushort4*>(&Bqh[(size_t)n * 2048 + k]) = hi;
    *reinterpret_cast<ushort4*>(&Bql[(size_t)n * 2048 + k]) = lo;
}

// ---------------------------------------------------------------------------
// Prep 3: o weights -> packed Bo [2048][2048] bf16 (hi only, signs baked)
// ---------------------------------------------------------------------------
__global__ __launch_bounds__(256) void prep_wo(
    const float* __restrict__ owr, const float* __restrict__ owi,
    short* __restrict__ Boh)
{
    int idx = blockIdx.x * 256 + threadIdx.x;        // 0 .. 2048*512-1
    int n = idx >> 9, kq = idx & 511;
    int k = kq * 4;
    int part = n >> 10, o = n & 1023;
    const float* W;
    float sgn;
    int kk;
    if (k < 1024) { W = part ? owi : owr; sgn = 1.f; kk = k; }
    else          { W = part ? owr : owi; sgn = part ? 1.f : -1.f; kk = k - 1024; }
    float4 v = *reinterpret_cast<const float4*>(W + (size_t)o * 1024 + kk);
    ushort4 hi;
    hi.x = (unsigned short)bf16_of(sgn * v.x);
    hi.y = (unsigned short)bf16_of(sgn * v.y);
    hi.z = (unsigned short)bf16_of(sgn * v.z);
    hi.w = (unsigned short)bf16_of(sgn * v.w);
    *reinterpret_cast<ushort4*>(&Boh[(size_t)n * 2048 + k]) = hi;
}

// ---------------------------------------------------------------------------
// GEMM-Q: [4096 x 2048] x [2048 x 2048] (Q cols only), 3-pass bf16 split.
// ---------------------------------------------------------------------------
__global__ __launch_bounds__(256) void gemm_q(
    const short* __restrict__ Zhi, const short* __restrict__ Zlo,
    const short* __restrict__ Bqh, const short* __restrict__ Bql,
    short* __restrict__ QKhi, short* __restrict__ QKlo)
{
    __shared__ __align__(16) short Ah[128][40], Al[128][40], Bh[128][40], Bl[128][40];
    const int tid = threadIdx.x;
    const int lane = tid & 63, wid = tid >> 6;
    const int c = lane & 15, g = lane >> 4;
    const int wr = wid >> 1, wc = wid & 1;
    const int nt = blockIdx.x, mt = blockIdx.y;
    const int m0 = mt * 128, n0 = nt * 128;

    const f4v zero4 = {0.f, 0.f, 0.f, 0.f};
    f4v acc[4][4];
#pragma unroll
    for (int mi = 0; mi < 4; ++mi)
#pragma unroll
        for (int ni = 0; ni < 4; ++ni) acc[mi][ni] = zero4;

    const int r2 = tid >> 2;            // 0..63
    const int koff = (tid & 3) * 8;     // 0,8,16,24

    for (int kt = 0; kt < 64; ++kt) {
        const int k0 = kt * 32;
        __syncthreads();
#pragma unroll
        for (int half = 0; half < 2; ++half) {
            int row = half * 64 + r2;
            size_t ga = (size_t)(m0 + row) * 2048 + k0 + koff;
            size_t gb = (size_t)(n0 + row) * 2048 + k0 + koff;
            *reinterpret_cast<s8v*>(&Ah[row][koff]) = *reinterpret_cast<const s8v*>(&Zhi[ga]);
            *reinterpret_cast<s8v*>(&Al[row][koff]) = *reinterpret_cast<const s8v*>(&Zlo[ga]);
            *reinterpret_cast<s8v*>(&Bh[row][koff]) = *reinterpret_cast<const s8v*>(&Bqh[gb]);
            *reinterpret_cast<s8v*>(&Bl[row][koff]) = *reinterpret_cast<const s8v*>(&Bql[gb]);
        }
        __syncthreads();

        s8v ah[4], alo[4], bh[4], blo[4];
#pragma unroll
        for (int i = 0; i < 4; ++i) {
            ah[i]  = *reinterpret_cast<const s8v*>(&Ah[wr * 64 + i * 16 + c][8 * g]);
            alo[i] = *reinterpret_cast<const s8v*>(&Al[wr * 64 + i * 16 + c][8 * g]);
            bh[i]  = *reinterpret_cast<const s8v*>(&Bh[wc * 64 + i * 16 + c][8 * g]);
            blo[i] = *reinterpret_cast<const s8v*>(&Bl[wc * 64 + i * 16 + c][8 * g]);
        }
        __builtin_amdgcn_s_setprio(1);
#pragma unroll
        for (int mi = 0; mi < 4; ++mi)
#pragma unroll
            for (int ni = 0; ni < 4; ++ni) {
                acc[mi][ni] = mf(ah[mi], bh[ni], acc[mi][ni]);
                acc[mi][ni] = mf(ah[mi], blo[ni], acc[mi][ni]);
                acc[mi][ni] = mf(alo[mi], bh[ni], acc[mi][ni]);
            }
        __builtin_amdgcn_s_setprio(0);
    }

    // epilogue: cols all < 2048 -> Q hi + lo
#pragma unroll
    for (int mi = 0; mi < 4; ++mi) {
#pragma unroll
        for (int ni = 0; ni < 4; ++ni) {
            int col = n0 + wc * 64 + ni * 16 + c;
            int rbase = m0 + wr * 64 + mi * 16 + 4 * g;
#pragma unroll
            for (int j = 0; j < 4; ++j) {
                short h, l;
                split2(acc[mi][ni][j], h, l);
                QKhi[(size_t)(rbase + j) * 4096 + col] = h;
                QKlo[(size_t)(rbase + j) * 2048 + col] = l;
            }
        }
    }
}

// ---------------------------------------------------------------------------
// GEMM-KV: [4096 x 2048] x [2048 x 4096] (K,V cols), single bf16 pass.
// ---------------------------------------------------------------------------
__global__ __launch_bounds__(256) void gemm_kv(
    const short* __restrict__ Zhi,
    const short* __restrict__ Bqh,
    short* __restrict__ QKhi,
    short* __restrict__ Vtr, short* __restrict__ Vti)
{
    __shared__ __align__(16) short Ah[128][40], Bh[128][40];
    const int tid = threadIdx.x;
    const int lane = tid & 63, wid = tid >> 6;
    const int c = lane & 15, g = lane >> 4;
    const int wr = wid >> 1, wc = wid & 1;
    const int nt = blockIdx.x, mt = blockIdx.y;
    const int m0 = mt * 128, n0 = 2048 + nt * 128;

    const f4v zero4 = {0.f, 0.f, 0.f, 0.f};
    f4v acc[4][4];
#pragma unroll
    for (int mi = 0; mi < 4; ++mi)
#pragma unroll
        for (int ni = 0; ni < 4; ++ni) acc[mi][ni] = zero4;

    const int r2 = tid >> 2;            // 0..63
    const int koff = (tid & 3) * 8;     // 0,8,16,24

    for (int kt = 0; kt < 64; ++kt) {
        const int k0 = kt * 32;
        __syncthreads();
#pragma unroll
        for (int half = 0; half < 2; ++half) {
            int row = half * 64 + r2;
            size_t ga = (size_t)(m0 + row) * 2048 + k0 + koff;
            size_t gb = (size_t)(n0 + row) * 2048 + k0 + koff;
            *reinterpret_cast<s8v*>(&Ah[row][koff]) = *reinterpret_cast<const s8v*>(&Zhi[ga]);
            *reinterpret_cast<s8v*>(&Bh[row][koff]) = *reinterpret_cast<const s8v*>(&Bqh[gb]);
        }
        __syncthreads();

        s8v ah[4], bh[4];
#pragma unroll
        for (int i = 0; i < 4; ++i) {
            ah[i] = *reinterpret_cast<const s8v*>(&Ah[wr * 64 + i * 16 + c][8 * g]);
            bh[i] = *reinterpret_cast<const s8v*>(&Bh[wc * 64 + i * 16 + c][8 * g]);
        }
        __builtin_amdgcn_s_setprio(1);
#pragma unroll
        for (int mi = 0; mi < 4; ++mi)
#pragma unroll
            for (int ni = 0; ni < 4; ++ni)
                acc[mi][ni] = mf(ah[mi], bh[ni], acc[mi][ni]);
        __builtin_amdgcn_s_setprio(0);
    }

    // epilogue: K cols -> QKhi; V cols -> V^T
#pragma unroll
    for (int mi = 0; mi < 4; ++mi) {
#pragma unroll
        for (int ni = 0; ni < 4; ++ni) {
            int col = n0 + wc * 64 + ni * 16 + c;
            int rbase = m0 + wr * 64 + mi * 16 + 4 * g;
            if (col < 4096) {
#pragma unroll
                for (int j = 0; j < 4; ++j)
                    QKhi[(size_t)(rbase + j) * 4096 + col] = bf16_of(acc[mi][ni][j]);
            } else {
                int cc = col - 4096;
                int part = cc >> 10, o = cc & 1023;
                int hh = o >> 6, d = o & 63;
                int bb = rbase >> 11, s = rbase & 2047;
                short* vt = part ? Vti : Vtr;
                ushort4 pk;
                pk.x = (unsigned short)bf16_of(acc[mi][ni][0]);
                pk.y = (unsigned short)bf16_of(acc[mi][ni][1]);
                pk.z = (unsigned short)bf16_of(acc[mi][ni][2]);
                pk.w = (unsigned short)bf16_of(acc[mi][ni][3]);
                *reinterpret_cast<ushort4*>(&vt[((size_t)(bb * 16 + hh) * 64 + d) * 2048 + s]) = pk;
            }
        }
    }
}

// ---------------------------------------------------------------------------
// Split-K flash attention: K AND V staged in LDS once per block (round-11,
// TA-instruction-minimized: 4 global instrs/wave/kt). Score math uses raw
// v_sqrt_f32 / v_exp_f32 (round-12: libm sqrtf/exp2f expand to guarded
// multi-instr sequences that made VALU the 68%-busy limiter).
// Swapped QK^T, flattened softmax, split-K x2, KVBLK=32.
// ---------------------------------------------------------------------------
__global__ __launch_bounds__(256) void attn_split(
    const short* __restrict__ QKhi, const short* __restrict__ QKlo,
    const short* __restrict__ Vtr, const short* __restrict__ Vti,
    float* __restrict__ Opart, float* __restrict__ Lp)
{
    __shared__ short kbuf[2][32][128];                 // 16 KB: row=key, [kr|ki], XOR slots
    __shared__ short vbuf[2][64][64];                  // 16 KB: row=d, [vr 32k|vi 32k], XOR slots
    __shared__ __align__(16) short p_lds[4][16][40];   // 5 KB per-wave P tiles
    const int tid = threadIdx.x, lane = tid & 63, wid = tid >> 6;
    const int c = lane & 15, g = lane >> 4;

    const int L = blockIdx.x;
    const int p = (L & 7) + ((L >> 9) << 3);     // (b,h) pair 0..31 (4 per XCD)
    const int j64 = (L >> 3) & 63;
    const int qt = j64 & 31;
    const int half = j64 >> 5;
    const int h = p & 15, b = p >> 4;
    const int kb0 = half * 1024;                 // first key of this block's range

    const int q0 = qt * 64 + wid * 16;
    const int mq = b * 2048 + q0 + c;

    s8v qrh[2], qrl[2], qih[2], qil[2], nqrh[2], nqrl[2];
#pragma unroll
    for (int ks = 0; ks < 2; ++ks) {
        int colr = h * 64 + ks * 32 + 8 * g;
        qrh[ks] = *reinterpret_cast<const s8v*>(&QKhi[(size_t)mq * 4096 + colr]);
        qrl[ks] = *reinterpret_cast<const s8v*>(&QKlo[(size_t)mq * 2048 + colr]);
        qih[ks] = *reinterpret_cast<const s8v*>(&QKhi[(size_t)mq * 4096 + 1024 + colr]);
        qil[ks] = *reinterpret_cast<const s8v*>(&QKlo[(size_t)mq * 2048 + 1024 + colr]);
        nqrh[ks] = qrh[ks] ^ (short)0x8000;
        nqrl[ks] = qrl[ks] ^ (short)0x8000;
    }

    // K staging: LDS row r holds key; physical 16B slot s holds logical
    // u = s^(r&7); u 0..7 = kr d[0..63], 8..15 = ki.
    const int srow = tid >> 4;                 // 0..15
    const int sslot = tid & 15;
    const int kslot_u = sslot ^ (srow & 7);
    const int gcolK = 2048 + (kslot_u >> 3) * 1024 + h * 64 + (kslot_u & 7) * 8;
    const short* gK = QKhi + (size_t)(b * 2048) * 4096 + gcolK;

    // V staging: vbuf row = d (0..63); physical slot s (0..7) holds logical
    // u = s^(d&7); u 0..3 = vr keys [8u..8u+7], u 4..7 = vi keys [8(u-4)..].
    const int vlr = lane >> 3;                  // local row 0..7
    const int vs = lane & 7;                    // physical slot
    const short* gV[2];
#pragma unroll
    for (int i = 0; i < 2; ++i) {
        int d = wid * 16 + i * 8 + vlr;
        int u = vs ^ (d & 7);
        const short* base = (u < 4) ? Vtr : Vti;
        gV[i] = base + (size_t)((b * 16 + h) * 64 + d) * 2048 + (u & 3) * 8;
    }

    const f4v zero4 = {0.f, 0.f, 0.f, 0.f};
    f4v aor[4], aoi[4];
#pragma unroll
    for (int dt = 0; dt < 4; ++dt) { aor[dt] = zero4; aoi[dt] = zero4; }
    float lrun = 0.f;        // all of this lane's scores belong to q = q0 + c

    // exp(s*0.125) == exp2(s*0.125*log2e)
    const float ESC = 0.125f * 1.44269504f;

    // prologue: stage tile 0 (K + V)
#pragma unroll
    for (int i = 0; i < 2; ++i) {
        __builtin_amdgcn_global_load_lds(
            gK + (size_t)(kb0 + i * 16 + srow) * 4096,
            &kbuf[0][i * 16 + wid * 4][0], 16, 0, 0);
        __builtin_amdgcn_global_load_lds(
            gV[i] + kb0,
            &vbuf[0][wid * 16 + i * 8][0], 16, 0, 0);
    }
    __syncthreads();

    for (int kt = 0; kt < 32; ++kt) {
        const int buf = kt & 1;
        if (kt + 1 < 32) {
            const int ko = kb0 + (kt + 1) * 32;
#pragma unroll
            for (int i = 0; i < 2; ++i) {
                __builtin_amdgcn_global_load_lds(
                    gK + (size_t)(ko + i * 16 + srow) * 4096,
                    &kbuf[buf ^ 1][i * 16 + wid * 4][0], 16, 0, 0);
                __builtin_amdgcn_global_load_lds(
                    gV[i] + ko,
                    &vbuf[buf ^ 1][wid * 16 + i * 8][0], 16, 0, 0);
            }
        }

#pragma unroll
        for (int kn = 0; kn < 2; ++kn) {
            f4v sr = zero4, si = zero4;
            const int row = kn * 16 + c;
#pragma unroll
            for (int ks = 0; ks < 2; ++ks) {
                const int sl = (((ks * 4 + g) ^ (c & 7))) * 8;
                s8v krh = *reinterpret_cast<const s8v*>(&kbuf[buf][row][sl]);
                s8v kih = *reinterpret_cast<const s8v*>(&kbuf[buf][row][sl + 64]);
                // swapped operands: lane(c,g) reg j = S[q=c][k=kn*16+4g+j]
                sr = mf(krh, qrh[ks], sr); sr = mf(krh, qrl[ks], sr);
                sr = mf(kih, qih[ks], sr); sr = mf(kih, qil[ks], sr);
                si = mf(krh, qih[ks], si); si = mf(krh, qil[ks], si);
                si = mf(kih, nqrh[ks], si); si = mf(kih, nqrl[ks], si);
            }
            float pv0, pv1, pv2, pv3;
            {
                float a, e;
                a = sr[0]; e = si[0];
                pv0 = hw_exp2(hw_sqrt(__builtin_fmaf(e, e, a * a)) * ESC);
                a = sr[1]; e = si[1];
                pv1 = hw_exp2(hw_sqrt(__builtin_fmaf(e, e, a * a)) * ESC);
                a = sr[2]; e = si[2];
                pv2 = hw_exp2(hw_sqrt(__builtin_fmaf(e, e, a * a)) * ESC);
                a = sr[3]; e = si[3];
                pv3 = hw_exp2(hw_sqrt(__builtin_fmaf(e, e, a * a)) * ESC);
            }
            lrun += (pv0 + pv1) + (pv2 + pv3);
            unsigned lo32, hi32;
            asm("v_cvt_pk_bf16_f32 %0, %1, %2" : "=v"(lo32) : "v"(pv0), "v"(pv1));
            asm("v_cvt_pk_bf16_f32 %0, %1, %2" : "=v"(hi32) : "v"(pv2), "v"(pv3));
            uint2 pk2; pk2.x = lo32; pk2.y = hi32;
            *reinterpret_cast<uint2*>(&p_lds[wid][c][kn * 16 + 4 * g]) = pk2;
        }

        // PV: P is [16q x 32k] per wave; V from shared vbuf (swizzled read)
        s8v pa = *reinterpret_cast<const s8v*>(&p_lds[wid][c][8 * g]);
#pragma unroll
        for (int dt = 0; dt < 4; ++dt) {
            const int d = dt * 16 + c;
            const int sr_ = (g ^ (d & 7)) * 8;          // vr logical slot g
            const int si_ = ((4 + g) ^ (d & 7)) * 8;    // vi logical slot 4+g
            s8v vr = *reinterpret_cast<const s8v*>(&vbuf[buf][d][sr_]);
            s8v vi = *reinterpret_cast<const s8v*>(&vbuf[buf][d][si_]);
            aor[dt] = mf(pa, vr, aor[dt]);
            aoi[dt] = mf(pa, vi, aoi[dt]);
        }
        __syncthreads();   // kbuf/vbuf[buf] free; next tile staged
    }

    // row-sum: lanes c, c+16, c+32, c+48 share q = q0 + c
    {
        float r = lrun;
        r += __shfl_xor(r, 16);
        r += __shfl_xor(r, 32);
        if (g == 0)
            Lp[(size_t)half * 65536 + ((b * 16 + h) << 11) + q0 + c] = r;
    }
    // partial O (fp32) -> Opart
#pragma unroll
    for (int dt = 0; dt < 4; ++dt) {
#pragma unroll
        for (int j = 0; j < 4; ++j) {
            int row = b * 2048 + q0 + 4 * g + j;
            size_t base = ((size_t)half * 4096 + row) * 2048 + h * 64 + dt * 16 + c;
            Opart[base] = aor[dt][j];
            Opart[base + 1024] = aoi[dt][j];
        }
    }
}

// ---------------------------------------------------------------------------
// Combine split-K partials: aout = (O0 + O1) / (l0 + l1), bf16.
// ---------------------------------------------------------------------------
__global__ __launch_bounds__(256) void combine(
    const float* __restrict__ Opart, const float* __restrict__ Lp,
    short* __restrict__ aout)
{
    int idx = blockIdx.x * 256 + threadIdx.x;     // 0 .. 1048575
    int r = idx >> 8, cg = idx & 255;
    int col = cg * 8;
    int b = r >> 11, q = r & 2047;
    int h = (col & 1023) >> 6;
    int lidx = ((b * 16 + h) << 11) + q;
    float li = 1.f / (Lp[lidx] + Lp[65536 + lidx]);
    size_t o0 = (size_t)r * 2048 + col;
    float4 a0 = *reinterpret_cast<const float4*>(Opart + o0);
    float4 a1 = *reinterpret_cast<const float4*>(Opart + o0 + 4);
    float4 b0 = *reinterpret_cast<const float4*>(Opart + 8388608 + o0);
    float4 b1 = *reinterpret_cast<const float4*>(Opart + 8388608 + o0 + 4);
    s8v u;
    u[0] = bf16_of((a0.x + b0.x) * li);
    u[1] = bf16_of((a0.y + b0.y) * li);
    u[2] = bf16_of((a0.z + b0.z) * li);
    u[3] = bf16_of((a0.w + b0.w) * li);
    u[4] = bf16_of((a1.x + b1.x) * li);
    u[5] = bf16_of((a1.y + b1.y) * li);
    u[6] = bf16_of((a1.z + b1.z) * li);
    u[7] = bf16_of((a1.w + b1.w) * li);
    *reinterpret_cast<s8v*>(&aout[o0]) = u;
}

// ---------------------------------------------------------------------------
// GEMM2: attn_out [4096 x 2048] x packed o_w bf16 [2048 x 2048] -> yr|yi fp32
// ---------------------------------------------------------------------------
__global__ __launch_bounds__(256) void gemm_out(
    const short* __restrict__ A,
    const short* __restrict__ Boh,
    float* __restrict__ out)
{
    __shared__ __align__(16) short Ah[128][40], Bh[128][40];
    const int tid = threadIdx.x;
    const int lane = tid & 63, wid = tid >> 6;
    const int c = lane & 15, g = lane >> 4;
    const int wr = wid >> 1, wc = wid & 1;
    const int nt = blockIdx.x, mt = blockIdx.y;
    const int m0 = mt * 128, n0 = nt * 128;

    const f4v zero4 = {0.f, 0.f, 0.f, 0.f};
    f4v acc[4][4];
#pragma unroll
    for (int mi = 0; mi < 4; ++mi)
#pragma unroll
        for (int ni = 0; ni < 4; ++ni) acc[mi][ni] = zero4;

    const int r2 = tid >> 2;
    const int koff = (tid & 3) * 8;

    for (int kt = 0; kt < 64; ++kt) {
        const int k0 = kt * 32;
        __syncthreads();
#pragma unroll
        for (int half = 0; half < 2; ++half) {
            int row = half * 64 + r2;
            *reinterpret_cast<s8v*>(&Ah[row][koff]) =
                *reinterpret_cast<const s8v*>(&A[(size_t)(m0 + row) * 2048 + k0 + koff]);
            *reinterpret_cast<s8v*>(&Bh[row][koff]) =
                *reinterpret_cast<const s8v*>(&Boh[(size_t)(n0 + row) * 2048 + k0 + koff]);
        }
        __syncthreads();

        s8v af[4], bfr[4];
#pragma unroll
        for (int i = 0; i < 4; ++i) {
            af[i]  = *reinterpret_cast<const s8v*>(&Ah[wr * 64 + i * 16 + c][8 * g]);
            bfr[i] = *reinterpret_cast<const s8v*>(&Bh[wc * 64 + i * 16 + c][8 * g]);
        }
        __builtin_amdgcn_s_setprio(1);
#pragma unroll
        for (int mi = 0; mi < 4; ++mi)
#pragma unroll
            for (int ni = 0; ni < 4; ++ni)
                acc[mi][ni] = mf(af[mi], bfr[ni], acc[mi][ni]);
        __builtin_amdgcn_s_setprio(0);
    }

#pragma unroll
    for (int mi = 0; mi < 4; ++mi)
#pragma unroll
        for (int ni = 0; ni < 4; ++ni) {
            int col = n0 + wc * 64 + ni * 16 + c;
#pragma unroll
            for (int j = 0; j < 4; ++j) {
                int row = m0 + wr * 64 + mi * 16 + 4 * g + j;
                float v = acc[mi][ni][j];
                if (col < 1024) out[(size_t)row * 1024 + col] = v;
                else out[4194304 + (size_t)row * 1024 + (col - 1024)] = v;
            }
        }
}

extern "C" void kernel_launch(void* const* d_in, const int* in_sizes, int n_in,
                              void* d_out, int out_size, void* d_ws, size_t ws_size,
                              hipStream_t stream) {
    const float* zr  = (const float*)d_in[0];
    const float* zi  = (const float*)d_in[1];
    const float* qwr = (const float*)d_in[2];
    const float* qwi = (const float*)d_in[3];
    const float* kwr = (const float*)d_in[4];
    const float* kwi = (const float*)d_in[5];
    const float* vwr = (const float*)d_in[6];
    const float* vwi = (const float*)d_in[7];
    const float* owr = (const float*)d_in[8];
    const float* owi = (const float*)d_in[9];

    char* ws = (char*)d_ws;
    short* QKhi = (short*)(ws);                      // 33554432 B
    short* QKlo = (short*)(ws + 33554432);           // 16777216 B (Q cols only)
    short* Vtr  = (short*)(ws + 50331648);           //  8388608 B
    short* Vti  = (short*)(ws + 58720256);           //  8388608 B
    short* aout = (short*)(ws + 67108864);           // 16777216 B
    short* Zhi  = (short*)(ws + 83886080);           // 16777216 B
    short* Zlo  = (short*)(ws + 100663296);          // 16777216 B
    short* Bqh  = (short*)(ws + 117440512);          // 25165824 B
    short* Bql  = (short*)(ws + 142606336);          // 25165824 B
    short* Boh  = (short*)(ws + 167772160);          //  8388608 B  (total 176160768)
    // split-K partials alias the prep buffers (dead after gemm_q/gemm_kv):
    float* Opart = (float*)(ws + 83886080);          // 67108864 B over Zhi..Bqh(+)
    float* Lp    = (float*)(ws + 150994944);         //   524288 B inside Bql

    prep_z<<<dim3(8192), 256, 0, stream>>>(zr, zi, Zhi, Zlo);
    prep_wqkv<<<dim3(12288), 256, 0, stream>>>(qwr, qwi, kwr, kwi, vwr, vwi, Bqh, Bql);
    prep_wo<<<dim3(4096), 256, 0, stream>>>(owr, owi, Boh);
    gemm_q<<<dim3(16, 32, 1), 256, 0, stream>>>(Zhi, Zlo, Bqh, Bql, QKhi, QKlo);
    gemm_kv<<<dim3(32, 32, 1), 256, 0, stream>>>(Zhi, Bqh, QKhi, Vtr, Vti);
    attn_split<<<dim3(2048), 256, 0, stream>>>(QKhi, QKlo, Vtr, Vti, Opart, Lp);
    combine<<<dim3(4096), 256, 0, stream>>>(Opart, Lp, aout);
    gemm_out<<<dim3(16, 32, 1), 256, 0, stream>>>(aout, Boh, (float*)d_out);
}